// Round 17
// baseline (323.866 us; speedup 1.0000x reference)
//
#include <hip/hip_runtime.h>

typedef unsigned short u16;
typedef __bf16 bf16x8 __attribute__((ext_vector_type(8)));
typedef float f32x4 __attribute__((ext_vector_type(4)));

// ---------- numeric helpers (RNE f32<->bf16, matching XLA/ml_dtypes) ----------
__device__ __forceinline__ u16 f2bf(float f){
  unsigned int x = __float_as_uint(f);
  unsigned int r = (x + 0x7FFFu + ((x >> 16) & 1u)) >> 16;
  return (u16)r;
}
__device__ __forceinline__ float bf2f(u16 u){
  return __uint_as_float(((unsigned int)u) << 16);
}
__device__ __forceinline__ int compute_u(int qvlv){
  int mm = qvlv > 2 ? qvlv : 2;
  int u = (int)(5.0 * log((double)mm));   // FACTOR=5.0, python int() truncation
  if (u < 1) u = 1;
  if (u > 64) u = 64;
  return u;
}
__device__ __forceinline__ void gload_lds16(const void* g, void* l){
  __builtin_amdgcn_global_load_lds(
      (const __attribute__((address_space(1))) void*)g,
      (__attribute__((address_space(3))) void*)l, 16, 0, 0);
}

// ---------- K1: split f32 -> 2 bf16 levels (16B stores); + WoT; + hmask ----------
// blocks [0,7680): expand X/W (8 floats/thread); [7680,8704): WoT transpose
__global__ void expand_kernel(const float* __restrict__ xq, const float* __restrict__ xk,
                              const float* __restrict__ xv,
                              const float* __restrict__ wq, const float* __restrict__ wk,
                              const float* __restrict__ wv,
                              u16* __restrict__ X1, u16* __restrict__ X2,
                              u16* __restrict__ W1, u16* __restrict__ W2,
                              const float* __restrict__ Wo, float* __restrict__ WoT,
                              unsigned int* __restrict__ hmask)
{
  __shared__ float tile[32][33];
  int t = threadIdx.x;
  if (blockIdx.x >= 7680){
    int bid = blockIdx.x - 7680;                // 0..1023
    int bx = (bid & 31) * 32, by = (bid >> 5) * 32;
    int tx = t & 31, ty = t >> 5;               // 32 x 8
#pragma unroll
    for (int r = 0; r < 4; ++r)
      tile[ty + r*8][tx] = Wo[(size_t)(by + ty + r*8) * 1024 + bx + tx];
    __syncthreads();
#pragma unroll
    for (int r = 0; r < 4; ++r)
      WoT[(size_t)(bx + ty + r*8) * 1024 + by + tx] = tile[tx][ty + r*8];
    return;
  }
  size_t g = (size_t)blockIdx.x * 256 + t;      // one group = 8 floats
  if (g < 4096) hmask[g] = 0;
  const float* src; u16 *d1, *d2;
  if (g < 1572864ull) {                 // X part: 3 * 4194304 / 8
    int p = (int)(g >> 19);
    size_t e = (g & 524287ull) * 8;
    src = (p == 0 ? xq : (p == 1 ? xk : xv)) + e;
    size_t o = (size_t)p * 4194304ull + e;
    d1 = X1 + o; d2 = X2 + o;
  } else {                              // W part: 3 * 1048576 / 8
    size_t wg = g - 1572864ull;
    int p = (int)(wg >> 17);
    size_t e = (wg & 131071ull) * 8;
    src = (p == 0 ? wq : (p == 1 ? wk : wv)) + e;
    size_t o = (size_t)p * 1048576ull + e;
    d1 = W1 + o; d2 = W2 + o;
  }
  float4 a = *reinterpret_cast<const float4*>(src);
  float4 b = *reinterpret_cast<const float4*>(src + 4);
  float xs[8] = {a.x, a.y, a.z, a.w, b.x, b.y, b.z, b.w};
  unsigned int hw[4], lw[4];
#pragma unroll
  for (int i = 0; i < 4; ++i){
    u16 h0 = f2bf(xs[2*i]);     u16 l0 = f2bf(xs[2*i]     - bf2f(h0));
    u16 h1 = f2bf(xs[2*i + 1]); u16 l1 = f2bf(xs[2*i + 1] - bf2f(h1));
    hw[i] = (unsigned int)h0 | ((unsigned int)h1 << 16);
    lw[i] = (unsigned int)l0 | ((unsigned int)l1 << 16);
  }
  *reinterpret_cast<uint4*>(d1) = make_uint4(hw[0], hw[1], hw[2], hw[3]);
  *reinterpret_cast<uint4*>(d2) = make_uint4(lw[0], lw[1], lw[2], lw[3]);
}

// ---------- K3: split-precision bf16 MFMA GEMM  C = X @ W^T + bias ----------
// R10 schedule skeleton; A planes staged to LDS (64KB dbuf), B operands in
// REGISTERS, prefetched one chunk ahead from L2-resident W planes (per-wave
// frags; two-body unrolled loop so all reg names are compile-time).
// Accumulation order bit-identical to R10/R16.
// z=0: Q -> f32 PROJ + qn; z=1: K -> KS split-bf16; z=2: V -> VT split-bf16 T.
__global__ __launch_bounds__(512, 1) void gemm_proj(
    const u16* __restrict__ X1, const u16* __restrict__ X2,
    const u16* __restrict__ W1, const u16* __restrict__ W2,
    const float* __restrict__ bq, const float* __restrict__ bk, const float* __restrict__ bv,
    float* __restrict__ PROJ, float* __restrict__ qn)
{
  int z = blockIdx.z;
  int orig = blockIdx.x + blockIdx.y * 8;          // 0..127
  int wgid = (orig & 7) * 16 + (orig >> 3);
  int bx = wgid & 7, by = wgid >> 3;

  const u16* Xa0 = X1 + (size_t)z * 4194304;
  const u16* Xa1 = X2 + (size_t)z * 4194304;
  const u16* Wb0 = W1 + (size_t)z * 1048576;
  const u16* Wb1 = W2 + (size_t)z * 1048576;
  const float* bias = (z == 0) ? bq : (z == 1 ? bk : bv);
  float* C = PROJ + (size_t)z * 4194304;

  // dbuf A tiles only: A0[256x32]@0, A1@8192 per set (16384 u16 = 32KB)
  __shared__ __align__(16) u16 T[2 * 16384];       // 64 KB
  u16* SET0 = T;
  u16* SET1 = T + 16384;

  int t = threadIdx.x;
  int wave = t >> 6, lane = t & 63;
  int wm = wave >> 1, wn = wave & 1;               // 4 x 2 wave grid
  int lr = lane & 15, lk = lane >> 4;
  int rowA = by * 256, rowB = bx * 128;
  f32x4 acc[4][4] = {};
  bf16x8 afA[4], afB[4];
  bf16x8 bgP0[4], bgP1[4], bgQ0[4], bgQ1[4];

#define STAGEA(dstbase, G)                                                    \
  {                                                                           \
    _Pragma("unroll")                                                         \
    for (int i = 0; i < 2; ++i){                                              \
      int p = i * 512 + t;                                                    \
      int r = p >> 2;                                                         \
      int c = (p & 3) ^ ((r >> 1) & 3);                                       \
      gload_lds16(G + (size_t)(rowA + r) * 1024 + pk + c * 8,                 \
                  (dstbase) + p * 8);                                         \
    }                                                                         \
  }
#define LOADBG(dst, G, PK)                                                    \
  {                                                                           \
    _Pragma("unroll")                                                         \
    for (int n = 0; n < 4; ++n){                                              \
      int r = rowB + wn * 64 + n * 16 + lr;                                   \
      dst[n] = *reinterpret_cast<const bf16x8*>(                              \
          G + (size_t)r * 1024 + (PK) + lk * 8);                              \
    }                                                                         \
  }
#define LOADA(dst, tile)                                                      \
  {                                                                           \
    _Pragma("unroll")                                                         \
    for (int m = 0; m < 4; ++m){                                              \
      int r = wm * 64 + m * 16 + lr;                                          \
      dst[m] = *reinterpret_cast<const bf16x8*>(                              \
          &(tile)[r * 32 + ((lk ^ ((r >> 1) & 3)) << 3)]);                    \
    }                                                                         \
  }
#define GRPX(A_, B_)                                                          \
  {                                                                           \
    __builtin_amdgcn_s_setprio(1);                                            \
    _Pragma("unroll")                                                         \
    for (int m = 0; m < 4; ++m)                                               \
      _Pragma("unroll")                                                       \
      for (int n = 0; n < 4; ++n)                                             \
        acc[m][n] = __builtin_amdgcn_mfma_f32_16x16x32_bf16(A_[m], B_[n],     \
                                                            acc[m][n], 0,0,0);\
    __builtin_amdgcn_s_setprio(0);                                            \
  }
// one K-chunk; PAR is a literal 0/1; CB* current B regs, NB* next B regs
#define CHUNK(KT, PAR, CB0, CB1, NB0, NB1)                                    \
  {                                                                           \
    u16* CUR = (PAR) ? SET1 : SET0;                                           \
    u16* NXT = (PAR) ? SET0 : SET1;                                           \
    if ((KT) < 31){                                                           \
      int pk = ((KT) + 1) * 32;                                               \
      STAGEA(NXT, Xa0); STAGEA(NXT + 8192, Xa1);                              \
      LOADBG(NB0, Wb0, pk);                                                   \
      LOADBG(NB1, Wb1, pk);                                                   \
    }                                                                         \
    __builtin_amdgcn_sched_barrier(0);                                        \
    u16* A0t = CUR;  u16* A1t = CUR + 8192;                                   \
    LOADA(afA, A0t); GRPX(afA, CB0);   /* A0*B0 */                            \
    LOADA(afB, A1t); GRPX(afA, CB1);   /* A0*B1 */                            \
                     GRPX(afB, CB0);   /* A1*B0 */                            \
    __syncthreads();                   /* drains vmcnt: NXT A + NB regs */    \
  }

  {                                    // prologue: stage chunk 0 (A + B regs)
    int pk = 0;
    STAGEA(SET0, Xa0); STAGEA(SET0 + 8192, Xa1);
    LOADBG(bgP0, Wb0, 0);
    LOADBG(bgP1, Wb1, 0);
  }
  __syncthreads();

  for (int kt = 0; kt < 32; kt += 2){
    CHUNK(kt,     0, bgP0, bgP1, bgQ0, bgQ1);
    CHUNK(kt + 1, 1, bgQ0, bgQ1, bgP0, bgP1);
  }
#undef STAGEA
#undef LOADBG
#undef LOADA
#undef GRPX
#undef CHUNK

  if (z == 0){
    float sq[4][4] = {};                      // [m][j] partial row-norms
#pragma unroll
    for (int m = 0; m < 4; ++m){
      int row0 = by * 256 + wm * 64 + m * 16 + lk * 4;
#pragma unroll
      for (int n = 0; n < 4; ++n){
        int col = bx * 128 + wn * 64 + n * 16 + lr;
        float bb = bias[col];
#pragma unroll
        for (int j = 0; j < 4; ++j){
          float v = acc[m][n][j] + bb;
          C[(size_t)(row0 + j) * 1024 + col] = v;
          sq[m][j] += v * v;
        }
      }
    }
    int hh = bx * 2 + wn;                     // this (bx,wn) covers head hh fully
#pragma unroll
    for (int m = 0; m < 4; ++m){
#pragma unroll
      for (int j = 0; j < 4; ++j){
        float s = sq[m][j];
        s += __shfl_xor(s, 1);
        s += __shfl_xor(s, 2);
        s += __shfl_xor(s, 4);
        s += __shfl_xor(s, 8);
        if (lr == 0){
          int row = by * 256 + wm * 64 + m * 16 + lk * 4 + j;
          qn[(size_t)((row >> 11) * 16 + hh) * 2048 + (row & 2047)] = s;
        }
      }
    }
  } else if (z == 1){
    u16* KS = (u16*)C;   // [32][2048][128] u16 (hi|lo planes)
#pragma unroll
    for (int m = 0; m < 4; ++m){
      int r0 = by * 256 + wm * 64 + m * 16 + lk * 4;
      int b = r0 >> 11, kb = r0 & 2047;
#pragma unroll
      for (int n = 0; n < 4; ++n){
        int c = bx * 128 + wn * 64 + n * 16 + lr;
        float bb = bias[c];
        int h = c >> 6, d = c & 63;
#pragma unroll
        for (int j = 0; j < 4; ++j){
          float v = acc[m][n][j] + bb;
          u16 hi = f2bf(v);
          u16 lo = f2bf(v - bf2f(hi));
          size_t base = ((size_t)(b * 16 + h) * 2048 + (size_t)(kb + j)) * 128;
          KS[base + d] = hi;
          KS[base + 64 + d] = lo;
        }
      }
    }
  } else {
    u16* VT = (u16*)C;   // [32][128][2048] u16
#pragma unroll
    for (int m = 0; m < 4; ++m){
      int r0 = by * 256 + wm * 64 + m * 16 + lk * 4;
      int b = r0 >> 11, kb = r0 & 2047;
#pragma unroll
      for (int n = 0; n < 4; ++n){
        int c = bx * 128 + wn * 64 + n * 16 + lr;
        float bb = bias[c];
        int h = c >> 6, d = c & 63;
        u16 hi[4], lo[4];
#pragma unroll
        for (int j = 0; j < 4; ++j){
          float v = acc[m][n][j] + bb;
          hi[j] = f2bf(v);
          lo[j] = f2bf(v - bf2f(hi[j]));
        }
        size_t base = ((size_t)(b * 16 + h) * 128) * 2048 + (size_t)kb;
        *reinterpret_cast<ushort4*>(&VT[base + (size_t)d * 2048]) =
            make_ushort4(hi[0], hi[1], hi[2], hi[3]);
        *reinterpret_cast<ushort4*>(&VT[base + (size_t)(64 + d) * 2048]) =
            make_ushort4(lo[0], lo[1], lo[2], lo[3]);
      }
    }
  }
}

// ---------- K5: top-u per (b,h): 1-wave barrier-free selection + QS gather ----------
__global__ __launch_bounds__(256) void topk_kernel(
    const float* __restrict__ qn, int* __restrict__ topk,
    unsigned char* __restrict__ seli, unsigned int* __restrict__ hmask,
    const float* __restrict__ PROJ, u16* __restrict__ QS,
    const int* __restrict__ qvlp){
  int bh = blockIdx.x; int b = bh >> 4, h = bh & 15;
  int u = compute_u(qvlp[0]);
  int t = threadIdx.x;
  __shared__ int sidx_l[64];
  if (t < 64){                              // wave 0 only: selection
    int lane = t;
    float v[32];
#pragma unroll
    for (int j = 0; j < 32; ++j) v[j] = qn[(size_t)bh * 2048 + j * 64 + lane];
    for (int it = 0; it < u; ++it){
      float bv = v[0]; int bi = lane;
#pragma unroll
      for (int j = 1; j < 32; ++j){
        if (v[j] > bv){ bv = v[j]; bi = j * 64 + lane; }   // strict >: lowest j
      }
#pragma unroll
      for (int off = 1; off < 64; off <<= 1){
        float ov = __shfl_xor(bv, off);
        int   oi = __shfl_xor(bi, off);
        if (ov > bv || (ov == bv && oi < bi)){ bv = ov; bi = oi; }
      }
      if (lane == 0){
        topk[bh * 64 + it] = bi;
        seli[(size_t)bh * 2048 + bi] = (unsigned char)it;
        atomicOr(&hmask[b * 2048 + bi], 1u << h);
        sidx_l[it] = bi;
      }
#pragma unroll
      for (int j = 0; j < 32; ++j)          // static-index suppression
        if (j * 64 + lane == bi) v[j] = -3.4e38f;
    }
  }
  __syncthreads();
  for (int e = t; e < 64 * 64; e += 256){   // gather phase: all 256 threads
    int i = e >> 6, d = e & 63;
    float v = 0.f;
    if (i < u) v = PROJ[(size_t)(b * 2048 + sidx_l[i]) * 1024 + h * 64 + d];
    u16 hi = f2bf(v);
    u16 lo = f2bf(v - bf2f(hi));
    QS[(size_t)bh * 8192 + i * 128 + d] = hi;
    QS[(size_t)bh * 8192 + i * 128 + 64 + d] = lo;
  }
}

// ---------- K6b: scores via MFMA: S = Q_sel @ K^T, bf16 round + bf16 mask add ----------
__global__ __launch_bounds__(256) void scores_mfma(
    const u16* __restrict__ QS, const u16* __restrict__ KS,
    const int* __restrict__ topk, const float* __restrict__ maskp,
    u16* __restrict__ sc, const int* __restrict__ qvlp, const int* __restrict__ kvlp)
{
  int bh = blockIdx.y;
  int kvlv = kvlp[0]; if (kvlv > 2048) kvlv = 2048; if (kvlv < 0) kvlv = 0;
  int u = compute_u(qvlp[0]);
  int k0 = blockIdx.x * 128;
  if (k0 >= kvlv) return;
  int t = threadIdx.x, wave = t >> 6, lane = t & 63;
  int lr = lane & 15, lk = lane >> 4;
  __shared__ int idx_l[64];
  if (t < 64) idx_l[t] = (t < u) ? topk[bh * 64 + t] : 0;
  __syncthreads();
  const u16* Qb = QS + (size_t)bh * 8192;
  const u16* Kb = KS + (size_t)bh * 2048 * 128;
  bf16x8 ah[2], al[2];
#pragma unroll
  for (int ks = 0; ks < 2; ++ks){
    const u16* qrow = &Qb[(wave * 16 + lr) * 128];
    ah[ks] = *reinterpret_cast<const bf16x8*>(&qrow[ks * 32 + lk * 8]);
    al[ks] = *reinterpret_cast<const bf16x8*>(&qrow[64 + ks * 32 + lk * 8]);
  }
  f32x4 acc[8] = {};
#pragma unroll
  for (int n = 0; n < 8; ++n){
    const u16* krow = &Kb[(size_t)(k0 + n * 16 + lr) * 128];
    bf16x8 bh0 = *reinterpret_cast<const bf16x8*>(&krow[lk * 8]);
    bf16x8 bh1 = *reinterpret_cast<const bf16x8*>(&krow[32 + lk * 8]);
    bf16x8 bl0 = *reinterpret_cast<const bf16x8*>(&krow[64 + lk * 8]);
    bf16x8 bl1 = *reinterpret_cast<const bf16x8*>(&krow[96 + lk * 8]);
    acc[n] = __builtin_amdgcn_mfma_f32_16x16x32_bf16(ah[0], bh0, acc[n], 0, 0, 0);
    acc[n] = __builtin_amdgcn_mfma_f32_16x16x32_bf16(ah[0], bl0, acc[n], 0, 0, 0);
    acc[n] = __builtin_amdgcn_mfma_f32_16x16x32_bf16(al[0], bh0, acc[n], 0, 0, 0);
    acc[n] = __builtin_amdgcn_mfma_f32_16x16x32_bf16(al[0], bl0, acc[n], 0, 0, 0);
    acc[n] = __builtin_amdgcn_mfma_f32_16x16x32_bf16(ah[1], bh1, acc[n], 0, 0, 0);
    acc[n] = __builtin_amdgcn_mfma_f32_16x16x32_bf16(ah[1], bl1, acc[n], 0, 0, 0);
    acc[n] = __builtin_amdgcn_mfma_f32_16x16x32_bf16(al[1], bh1, acc[n], 0, 0, 0);
    acc[n] = __builtin_amdgcn_mfma_f32_16x16x32_bf16(al[1], bl1, acc[n], 0, 0, 0);
  }
#pragma unroll
  for (int n = 0; n < 8; ++n){
    int k = k0 + n * 16 + lr;
    if (k >= kvlv) continue;
#pragma unroll
    for (int j = 0; j < 4; ++j){
      int i = wave * 16 + lk * 4 + j;
      if (i >= u) continue;
      float s = acc[n][j] * 0.125f;               // / sqrt(64)
      u16 xb = f2bf(s);                           // scores.astype(bf16)
      u16 mb = f2bf(maskp[(size_t)idx_l[i] * 2048 + k]);  // attn_mask.astype(bf16)
      u16 xm = f2bf(bf2f(xb) + bf2f(mb));         // bf16 add
      sc[(size_t)(bh * 64 + i) * 2048 + k] = xm;
    }
  }
}

// ---------- K7: exact bf16 softmax emulation; p written in place ----------
__global__ void softmax_kernel(u16* __restrict__ sc, const int* __restrict__ qvlp,
                               const int* __restrict__ kvlp){
  int bh = blockIdx.y, i = blockIdx.x;
  int u = compute_u(qvlp[0]);
  if (i >= u) return;
  int kvlv = kvlp[0]; if (kvlv > 2048) kvlv = 2048; if (kvlv < 0) kvlv = 0;
  u16* row = sc + (size_t)(bh * 64 + i) * 2048;
  int t = threadIdx.x;
  float x[8];
  float lm = -3.4e38f;
#pragma unroll
  for (int j = 0; j < 8; ++j){
    int k = t + j * 256;
    x[j] = (k < kvlv) ? bf2f(row[k]) : -3.4e38f;
    lm = fmaxf(lm, x[j]);
  }
  __shared__ float red[256];
  red[t] = lm; __syncthreads();
  for (int s = 128; s > 0; s >>= 1){ if (t < s) red[t] = fmaxf(red[t], red[t+s]); __syncthreads(); }
  float m = red[0];
  __syncthreads();
  float e[8]; float ls = 0.f;
#pragma unroll
  for (int j = 0; j < 8; ++j){
    int k = t + j * 256;
    if (k < kvlv){
      u16 ub = f2bf(x[j] - m);            // bf16 subtract
      u16 eb = f2bf(expf(bf2f(ub)));      // bf16 exp
      e[j] = bf2f(eb);
      ls += e[j];
    } else e[j] = 0.f;
  }
  red[t] = ls; __syncthreads();
  for (int s = 128; s > 0; s >>= 1){ if (t < s) red[t] += red[t+s]; __syncthreads(); }
  float S = red[0];                       // f32 accumulation (jnp.sum upcast)
  float Sb = bf2f(f2bf(S));               // downcast back to bf16
#pragma unroll
  for (int j = 0; j < 8; ++j){
    int k = t + j * 256;
    if (k < 2048) row[k] = (k < kvlv) ? f2bf(e[j] / Sb) : (u16)0;   // bf16 divide
  }
}

// ---------- K8a: PV via MFMA, no LDS. part[kc][bh][64 rows][64 d] ----------
__global__ void pv_mfma(const u16* __restrict__ probs, const u16* __restrict__ VT,
                        float* __restrict__ part, const int* __restrict__ kvlp)
{
  int bh = blockIdx.y; int b = bh >> 4, h = bh & 15;
  int kvlv = kvlp[0]; if (kvlv > 2048) kvlv = 2048; if (kvlv < 0) kvlv = 0;
  int kc = blockIdx.x;
  int k0 = kc * 128;
  if (k0 >= kvlv) return;
  int t = threadIdx.x, w = t >> 6, lane = t & 63;
  int lr = lane & 15, lk = lane >> 4;
  const u16* Pb = probs + (size_t)bh * 64 * 2048;
  const u16* Vb = VT + (size_t)(b * 16 + h) * 128 * 2048;
  f32x4 acc[4] = {};
#pragma unroll
  for (int ks = 0; ks < 4; ++ks){
    int kk = k0 + ks * 32 + lk * 8;
    bf16x8 A0 = *reinterpret_cast<const bf16x8*>(Pb + (size_t)(lr     ) * 2048 + kk);
    bf16x8 A1 = *reinterpret_cast<const bf16x8*>(Pb + (size_t)(lr + 16) * 2048 + kk);
    bf16x8 A2 = *reinterpret_cast<const bf16x8*>(Pb + (size_t)(lr + 32) * 2048 + kk);
    bf16x8 A3 = *reinterpret_cast<const bf16x8*>(Pb + (size_t)(lr + 48) * 2048 + kk);
    bf16x8 Bh = *reinterpret_cast<const bf16x8*>(Vb + (size_t)(w * 16 + lr     ) * 2048 + kk);
    bf16x8 Bl = *reinterpret_cast<const bf16x8*>(Vb + (size_t)(w * 16 + lr + 64) * 2048 + kk);
    acc[0] = __builtin_amdgcn_mfma_f32_16x16x32_bf16(A0, Bh, acc[0], 0, 0, 0);
    acc[1] = __builtin_amdgcn_mfma_f32_16x16x32_bf16(A1, Bh, acc[1], 0, 0, 0);
    acc[2] = __builtin_amdgcn_mfma_f32_16x16x32_bf16(A2, Bh, acc[2], 0, 0, 0);
    acc[3] = __builtin_amdgcn_mfma_f32_16x16x32_bf16(A3, Bh, acc[3], 0, 0, 0);
    acc[0] = __builtin_amdgcn_mfma_f32_16x16x32_bf16(A0, Bl, acc[0], 0, 0, 0);
    acc[1] = __builtin_amdgcn_mfma_f32_16x16x32_bf16(A1, Bl, acc[1], 0, 0, 0);
    acc[2] = __builtin_amdgcn_mfma_f32_16x16x32_bf16(A2, Bl, acc[2], 0, 0, 0);
    acc[3] = __builtin_amdgcn_mfma_f32_16x16x32_bf16(A3, Bl, acc[3], 0, 0, 0);
  }
  float* pc = part + (size_t)(kc * 32 + bh) * 64 * 64;
#pragma unroll
  for (int m = 0; m < 4; ++m){
    int row = m * 16 + lk * 4;
#pragma unroll
    for (int j = 0; j < 4; ++j)
      pc[(size_t)(row + j) * 64 + w * 16 + lr] = acc[m][j];
  }
}

// ---------- K9: sparse output projection; sums PV partials inline ----------
__global__ void outproj_kernel(const float* __restrict__ part, const float* __restrict__ WoT,
                               const float* __restrict__ bo, const unsigned int* __restrict__ hmask,
                               const unsigned char* __restrict__ seli, float* __restrict__ out,
                               const int* __restrict__ kvlp){
  int row = blockIdx.x;                 // b*2048 + l
  int b = row >> 11, l = row & 2047;
  int t = threadIdx.x;
  int kvlv = kvlp[0]; if (kvlv > 2048) kvlv = 2048; if (kvlv < 0) kvlv = 0;
  int kcmax = (kvlv + 127) / 128;
  float acc[4];
#pragma unroll
  for (int r = 0; r < 4; ++r) acc[r] = bo[t + r * 256];
  unsigned int m = hmask[row];
  __shared__ float clds[64];
  while (m){
    int h = __ffs(m) - 1; m &= (m - 1);
    int bh = b * 16 + h;
    int i = (int)seli[(size_t)bh * 2048 + l];
    __syncthreads();
    if (t < 64){
      float s = 0.f;
      for (int kc = 0; kc < kcmax; ++kc)
        s += part[(size_t)((kc * 32 + bh) * 64 + i) * 64 + t];
      clds[t] = s;
    }
    __syncthreads();
    for (int j = 0; j < 64; ++j){
      float c = clds[j];
      const float* wrow = &WoT[(size_t)(h * 64 + j) * 1024];
#pragma unroll
      for (int r = 0; r < 4; ++r) acc[r] += c * wrow[t + r * 256];
    }
  }
  float* orow = out + (size_t)row * 1024;
#pragma unroll
  for (int r = 0; r < 4; ++r) orow[t + r * 256] = acc[r];
}

__global__ void fail_fill(float* o, int n){
  int i = blockIdx.x * 256 + threadIdx.x;
  if (i < n) o[i] = 12345.0f;
}

// ---------------------------------------------------------------------------
extern "C" void kernel_launch(void* const* d_in, const int* in_sizes, int n_in,
                              void* d_out, int out_size, void* d_ws, size_t ws_size,
                              hipStream_t stream)
{
  const float* query = (const float*)d_in[0];
  const float* key   = (const float*)d_in[1];
  const float* value = (const float*)d_in[2];
  const float* maskp = (const float*)d_in[3];
  const float* Wq = (const float*)d_in[4];
  const float* bq = (const float*)d_in[5];
  const float* Wk = (const float*)d_in[6];
  const float* bk = (const float*)d_in[7];
  const float* Wv = (const float*)d_in[8];
  const float* bv = (const float*)d_in[9];
  const float* Wo = (const float*)d_in[10];
  const float* bo = (const float*)d_in[11];
  const int* qvl = (const int*)d_in[12];
  const int* kvl = (const int*)d_in[13];
  float* out = (float*)d_out;

  char* ws = (char*)d_ws;
  size_t off = 0;
  auto alloc = [&](size_t bytes) -> void* {
    void* p = ws + off;
    off = (off + bytes + 255) & ~(size_t)255;
    return p;
  };
  u16* X1 = (u16*)alloc(3ull * 4194304 * 2);
  u16* X2 = (u16*)alloc(3ull * 4194304 * 2);
  u16* W1 = (u16*)alloc(3ull * 1048576 * 2);
  u16* W2 = (u16*)alloc(3ull * 1048576 * 2);
  float* PROJ = (float*)alloc(3ull * 4194304 * 4);
  float* WOT  = (float*)alloc(4194304ull);
  float* QN   = (float*)alloc(2ull * 16 * 2048 * 4);
  int*   TOPK = (int*)alloc(2ull * 16 * 64 * 4);
  unsigned char* SELI = (unsigned char*)alloc(2ull * 16 * 2048);
  unsigned int* HMASK = (unsigned int*)alloc(2ull * 2048 * 4);
  u16*   SC   = (u16*)alloc(2048ull * 2048 * 2);
  u16*   QS   = (u16*)alloc(32ull * 64 * 128 * 2);

  // KS (split-bf16 K) aliases the PROJ z==1 slice (exactly 16.78 MB)
  u16* KS = (u16*)(PROJ + 1ull * 4194304);
  // VT (split-bf16 transposed V) aliases the PROJ z==2 slice (exactly 16.78 MB)
  u16* VT = (u16*)(PROJ + 2ull * 4194304);
  // PV partials alias X1 (24 MB, dead after gemm_proj): 16*32*64*64*4 = 8.4 MB
  float* PART = (float*)X1;

  if (ws_size < off){
    fail_fill<<<(out_size + 255) / 256, 256, 0, stream>>>(out, out_size);
    return;
  }

  expand_kernel<<<8704, 256, 0, stream>>>(query, key, value, Wq, Wk, Wv,
                                          X1, X2, W1, W2, Wo, WOT, HMASK);
  gemm_proj<<<dim3(8, 16, 3), 512, 0, stream>>>(X1, X2, W1, W2, bq, bk, bv, PROJ, QN);
  topk_kernel<<<32, 256, 0, stream>>>(QN, TOPK, SELI, HMASK, PROJ, QS, qvl);
  scores_mfma<<<dim3(16, 32), 256, 0, stream>>>(QS, KS, TOPK, maskp, SC, qvl, kvl);
  softmax_kernel<<<dim3(64, 32), 256, 0, stream>>>(SC, qvl, kvl);
  pv_mfma<<<dim3(16, 32), 256, 0, stream>>>(SC, VT, PART, kvl);
  outproj_kernel<<<4096, 256, 0, stream>>>(PART, WOT, bo, HMASK, SELI, out, kvl);
}

// Round 18
// 221.366 us; speedup vs baseline: 1.4630x; 1.4630x over previous
//
#include <hip/hip_runtime.h>

typedef unsigned short u16;
typedef __bf16 bf16x8 __attribute__((ext_vector_type(8)));
typedef float f32x4 __attribute__((ext_vector_type(4)));

// ---------- numeric helpers (RNE f32<->bf16, matching XLA/ml_dtypes) ----------
__device__ __forceinline__ u16 f2bf(float f){
  unsigned int x = __float_as_uint(f);
  unsigned int r = (x + 0x7FFFu + ((x >> 16) & 1u)) >> 16;
  return (u16)r;
}
__device__ __forceinline__ float bf2f(u16 u){
  return __uint_as_float(((unsigned int)u) << 16);
}
__device__ __forceinline__ int compute_u(int qvlv){
  int mm = qvlv > 2 ? qvlv : 2;
  int u = (int)(5.0 * log((double)mm));   // FACTOR=5.0, python int() truncation
  if (u < 1) u = 1;
  if (u > 64) u = 64;
  return u;
}
__device__ __forceinline__ void gload_lds16(const void* g, void* l){
  __builtin_amdgcn_global_load_lds(
      (const __attribute__((address_space(1))) void*)g,
      (__attribute__((address_space(3))) void*)l, 16, 0, 0);
}

// ---------- K1: split f32 -> 2 bf16 levels (16B stores); X: q/k/v, W: Wq/Wk/Wv/Wo ----------
// 8192 blocks exactly (X 1572864 groups + W 524288 groups, 8 floats/group).
// Also zeroes hmask.
__global__ void expand_kernel(const float* __restrict__ xq, const float* __restrict__ xk,
                              const float* __restrict__ xv,
                              const float* __restrict__ wq, const float* __restrict__ wk,
                              const float* __restrict__ wv, const float* __restrict__ wo,
                              u16* __restrict__ X1, u16* __restrict__ X2,
                              u16* __restrict__ W1, u16* __restrict__ W2,
                              u16* __restrict__ WO1, u16* __restrict__ WO2,
                              unsigned int* __restrict__ hmask)
{
  int t = threadIdx.x;
  size_t g = (size_t)blockIdx.x * 256 + t;      // one group = 8 floats
  if (g < 4096) hmask[g] = 0;
  const float* src; u16 *d1, *d2;
  if (g < 1572864ull) {                 // X part: 3 * 4194304 / 8
    int p = (int)(g >> 19);
    size_t e = (g & 524287ull) * 8;
    src = (p == 0 ? xq : (p == 1 ? xk : xv)) + e;
    size_t o = (size_t)p * 4194304ull + e;
    d1 = X1 + o; d2 = X2 + o;
  } else {                              // W part: 4 * 1048576 / 8
    size_t wg = g - 1572864ull;
    int p = (int)(wg >> 17);
    size_t e = (wg & 131071ull) * 8;
    src = (p == 0 ? wq : (p == 1 ? wk : (p == 2 ? wv : wo))) + e;
    if (p < 3){
      size_t o = (size_t)p * 1048576ull + e;
      d1 = W1 + o; d2 = W2 + o;
    } else {
      d1 = WO1 + e; d2 = WO2 + e;
    }
  }
  float4 a = *reinterpret_cast<const float4*>(src);
  float4 b = *reinterpret_cast<const float4*>(src + 4);
  float xs[8] = {a.x, a.y, a.z, a.w, b.x, b.y, b.z, b.w};
  unsigned int hw[4], lw[4];
#pragma unroll
  for (int i = 0; i < 4; ++i){
    u16 h0 = f2bf(xs[2*i]);     u16 l0 = f2bf(xs[2*i]     - bf2f(h0));
    u16 h1 = f2bf(xs[2*i + 1]); u16 l1 = f2bf(xs[2*i + 1] - bf2f(h1));
    hw[i] = (unsigned int)h0 | ((unsigned int)h1 << 16);
    lw[i] = (unsigned int)l0 | ((unsigned int)l1 << 16);
  }
  *reinterpret_cast<uint4*>(d1) = make_uint4(hw[0], hw[1], hw[2], hw[3]);
  *reinterpret_cast<uint4*>(d2) = make_uint4(lw[0], lw[1], lw[2], lw[3]);
}

// ---------- K3: split-precision bf16 MFMA GEMM  C = X @ W^T + bias ----------
// R10/R16-validated schedule (FROZEN). z=0: Q -> f32 PROJ + qn;
// z=1: K -> KS split-bf16 [b,h][key][128]; z=2: V -> VT split-bf16 T.
__global__ __launch_bounds__(512, 1) void gemm_proj(
    const u16* __restrict__ X1, const u16* __restrict__ X2,
    const u16* __restrict__ W1, const u16* __restrict__ W2,
    const float* __restrict__ bq, const float* __restrict__ bk, const float* __restrict__ bv,
    float* __restrict__ PROJ, float* __restrict__ qn)
{
  int z = blockIdx.z;
  int orig = blockIdx.x + blockIdx.y * 8;          // 0..127
  int wgid = (orig & 7) * 16 + (orig >> 3);
  int bx = wgid & 7, by = wgid >> 3;

  const u16* Xa0 = X1 + (size_t)z * 4194304;
  const u16* Xa1 = X2 + (size_t)z * 4194304;
  const u16* Wb0 = W1 + (size_t)z * 1048576;
  const u16* Wb1 = W2 + (size_t)z * 1048576;
  const float* bias = (z == 0) ? bq : (z == 1 ? bk : bv);
  float* C = PROJ + (size_t)z * 4194304;

  __shared__ __align__(16) u16 T[2 * 24576];       // 96 KB
  u16* SET0 = T;
  u16* SET1 = T + 24576;

  int t = threadIdx.x;
  int wave = t >> 6, lane = t & 63;
  int wm = wave >> 1, wn = wave & 1;               // 4 x 2 wave grid
  int lr = lane & 15, lk = lane >> 4;
  int rowA = by * 256, rowB = bx * 128;
  f32x4 acc[4][4] = {};
  bf16x8 afA[4], afB[4], bgA[4], bgB[4];

#define STAGEA(dstbase, G)                                                    \
  {                                                                           \
    _Pragma("unroll")                                                         \
    for (int i = 0; i < 2; ++i){                                              \
      int p = i * 512 + t;                                                    \
      int r = p >> 2;                                                         \
      int c = (p & 3) ^ ((r >> 1) & 3);                                       \
      gload_lds16(G + (size_t)(rowA + r) * 1024 + pk + c * 8,                 \
                  (dstbase) + p * 8);                                         \
    }                                                                         \
  }
#define STAGEB(dstbase, G)                                                    \
  {                                                                           \
    int p = t;                                                                \
    int r = p >> 2;                                                           \
    int c = (p & 3) ^ ((r >> 1) & 3);                                         \
    gload_lds16(G + (size_t)(rowB + r) * 1024 + pk + c * 8,                   \
                (dstbase) + p * 8);                                           \
  }
#define STAGE_SET(S)                                                          \
  {                                                                           \
    STAGEA((S), Xa0); STAGEA((S) + 8192, Xa1);                                \
    STAGEB((S) + 16384, Wb0); STAGEB((S) + 20480, Wb1);                       \
  }
#define LOADA(dst, tile)                                                      \
  {                                                                           \
    _Pragma("unroll")                                                         \
    for (int m = 0; m < 4; ++m){                                              \
      int r = wm * 64 + m * 16 + lr;                                          \
      dst[m] = *reinterpret_cast<const bf16x8*>(                              \
          &(tile)[r * 32 + ((lk ^ ((r >> 1) & 3)) << 3)]);                    \
    }                                                                         \
  }
#define LOADB(dst, tile)                                                      \
  {                                                                           \
    _Pragma("unroll")                                                         \
    for (int n = 0; n < 4; ++n){                                              \
      int r = wn * 64 + n * 16 + lr;                                          \
      dst[n] = *reinterpret_cast<const bf16x8*>(                              \
          &(tile)[r * 32 + ((lk ^ ((r >> 1) & 3)) << 3)]);                    \
    }                                                                         \
  }
#define GRPX(A_, B_)                                                          \
  {                                                                           \
    __builtin_amdgcn_s_setprio(1);                                            \
    _Pragma("unroll")                                                         \
    for (int m = 0; m < 4; ++m)                                               \
      _Pragma("unroll")                                                       \
      for (int n = 0; n < 4; ++n)                                             \
        acc[m][n] = __builtin_amdgcn_mfma_f32_16x16x32_bf16(A_[m], B_[n],     \
                                                            acc[m][n], 0,0,0);\
    __builtin_amdgcn_s_setprio(0);                                            \
  }

  {                                    // prologue: stage chunk 0
    int pk = 0;
    STAGE_SET(SET0);
  }
  __syncthreads();

  for (int kt = 0; kt < 32; ++kt){
    u16* CUR = (kt & 1) ? SET1 : SET0;
    u16* NXT = (kt & 1) ? SET0 : SET1;
    if (kt < 31){
      int pk = (kt + 1) * 32;
      STAGE_SET(NXT);                  // issue next-chunk loads (hidden under MFMA)
    }
    __builtin_amdgcn_sched_barrier(0); // keep stage-issue ahead of compute
    u16* A0t = CUR;          u16* A1t = CUR + 8192;
    u16* B0t = CUR + 16384;  u16* B1t = CUR + 20480;
    LOADA(afA, A0t); LOADB(bgA, B0t);
    LOADB(bgB, B1t); GRPX(afA, bgA);   // A0*B0
    LOADA(afB, A1t); GRPX(afA, bgB);   // A0*B1
                     GRPX(afB, bgA);   // A1*B0
    __syncthreads();                   // drains vmcnt: next chunk staged & visible
  }
#undef STAGEA
#undef STAGEB
#undef STAGE_SET
#undef LOADA
#undef LOADB
#undef GRPX

  if (z == 0){
    float sq[4][4] = {};                      // [m][j] partial row-norms
#pragma unroll
    for (int m = 0; m < 4; ++m){
      int row0 = by * 256 + wm * 64 + m * 16 + lk * 4;
#pragma unroll
      for (int n = 0; n < 4; ++n){
        int col = bx * 128 + wn * 64 + n * 16 + lr;
        float bb = bias[col];
#pragma unroll
        for (int j = 0; j < 4; ++j){
          float v = acc[m][n][j] + bb;
          C[(size_t)(row0 + j) * 1024 + col] = v;
          sq[m][j] += v * v;
        }
      }
    }
    int hh = bx * 2 + wn;                     // this (bx,wn) covers head hh fully
#pragma unroll
    for (int m = 0; m < 4; ++m){
#pragma unroll
      for (int j = 0; j < 4; ++j){
        float s = sq[m][j];
        s += __shfl_xor(s, 1);
        s += __shfl_xor(s, 2);
        s += __shfl_xor(s, 4);
        s += __shfl_xor(s, 8);
        if (lr == 0){
          int row = by * 256 + wm * 64 + m * 16 + lk * 4 + j;
          qn[(size_t)((row >> 11) * 16 + hh) * 2048 + (row & 2047)] = s;
        }
      }
    }
  } else if (z == 1){
    u16* KS = (u16*)C;   // [32][2048][128] u16 (hi|lo planes)
#pragma unroll
    for (int m = 0; m < 4; ++m){
      int r0 = by * 256 + wm * 64 + m * 16 + lk * 4;
      int b = r0 >> 11, kb = r0 & 2047;
#pragma unroll
      for (int n = 0; n < 4; ++n){
        int c = bx * 128 + wn * 64 + n * 16 + lr;
        float bb = bias[c];
        int h = c >> 6, d = c & 63;
#pragma unroll
        for (int j = 0; j < 4; ++j){
          float v = acc[m][n][j] + bb;
          u16 hi = f2bf(v);
          u16 lo = f2bf(v - bf2f(hi));
          size_t base = ((size_t)(b * 16 + h) * 2048 + (size_t)(kb + j)) * 128;
          KS[base + d] = hi;
          KS[base + 64 + d] = lo;
        }
      }
    }
  } else {
    u16* VT = (u16*)C;   // [32][128][2048] u16
#pragma unroll
    for (int m = 0; m < 4; ++m){
      int r0 = by * 256 + wm * 64 + m * 16 + lk * 4;
      int b = r0 >> 11, kb = r0 & 2047;
#pragma unroll
      for (int n = 0; n < 4; ++n){
        int c = bx * 128 + wn * 64 + n * 16 + lr;
        float bb = bias[c];
        int h = c >> 6, d = c & 63;
        u16 hi[4], lo[4];
#pragma unroll
        for (int j = 0; j < 4; ++j){
          float v = acc[m][n][j] + bb;
          hi[j] = f2bf(v);
          lo[j] = f2bf(v - bf2f(hi[j]));
        }
        size_t base = ((size_t)(b * 16 + h) * 128) * 2048 + (size_t)kb;
        *reinterpret_cast<ushort4*>(&VT[base + (size_t)d * 2048]) =
            make_ushort4(hi[0], hi[1], hi[2], hi[3]);
        *reinterpret_cast<ushort4*>(&VT[base + (size_t)(64 + d) * 2048]) =
            make_ushort4(lo[0], lo[1], lo[2], lo[3]);
      }
    }
  }
}

// ---------- K5: top-u per (b,h): 1-wave barrier-free selection + QS gather ----------
__global__ __launch_bounds__(256) void topk_kernel(
    const float* __restrict__ qn, int* __restrict__ topk,
    unsigned char* __restrict__ seli, unsigned int* __restrict__ hmask,
    const float* __restrict__ PROJ, u16* __restrict__ QS,
    const int* __restrict__ qvlp){
  int bh = blockIdx.x; int b = bh >> 4, h = bh & 15;
  int u = compute_u(qvlp[0]);
  int t = threadIdx.x;
  __shared__ int sidx_l[64];
  if (t < 64){                              // wave 0 only: selection
    int lane = t;
    float v[32];
#pragma unroll
    for (int j = 0; j < 32; ++j) v[j] = qn[(size_t)bh * 2048 + j * 64 + lane];
    for (int it = 0; it < u; ++it){
      float bv = v[0]; int bi = lane;
#pragma unroll
      for (int j = 1; j < 32; ++j){
        if (v[j] > bv){ bv = v[j]; bi = j * 64 + lane; }   // strict >: lowest j
      }
#pragma unroll
      for (int off = 1; off < 64; off <<= 1){
        float ov = __shfl_xor(bv, off);
        int   oi = __shfl_xor(bi, off);
        if (ov > bv || (ov == bv && oi < bi)){ bv = ov; bi = oi; }
      }
      if (lane == 0){
        topk[bh * 64 + it] = bi;
        seli[(size_t)bh * 2048 + bi] = (unsigned char)it;
        atomicOr(&hmask[b * 2048 + bi], 1u << h);
        sidx_l[it] = bi;
      }
#pragma unroll
      for (int j = 0; j < 32; ++j)          // static-index suppression
        if (j * 64 + lane == bi) v[j] = -3.4e38f;
    }
  }
  __syncthreads();
  for (int e = t; e < 64 * 64; e += 256){   // gather phase: all 256 threads
    int i = e >> 6, d = e & 63;
    float v = 0.f;
    if (i < u) v = PROJ[(size_t)(b * 2048 + sidx_l[i]) * 1024 + h * 64 + d];
    u16 hi = f2bf(v);
    u16 lo = f2bf(v - bf2f(hi));
    QS[(size_t)bh * 8192 + i * 128 + d] = hi;
    QS[(size_t)bh * 8192 + i * 128 + 64 + d] = lo;
  }
}

// ---------- K6b: scores via MFMA: S = Q_sel @ K^T, bf16 round + bf16 mask add ----------
__global__ __launch_bounds__(256) void scores_mfma(
    const u16* __restrict__ QS, const u16* __restrict__ KS,
    const int* __restrict__ topk, const float* __restrict__ maskp,
    u16* __restrict__ sc, const int* __restrict__ qvlp, const int* __restrict__ kvlp)
{
  int bh = blockIdx.y;
  int kvlv = kvlp[0]; if (kvlv > 2048) kvlv = 2048; if (kvlv < 0) kvlv = 0;
  int u = compute_u(qvlp[0]);
  int k0 = blockIdx.x * 128;
  if (k0 >= kvlv) return;
  int t = threadIdx.x, wave = t >> 6, lane = t & 63;
  int lr = lane & 15, lk = lane >> 4;
  __shared__ int idx_l[64];
  if (t < 64) idx_l[t] = (t < u) ? topk[bh * 64 + t] : 0;
  __syncthreads();
  const u16* Qb = QS + (size_t)bh * 8192;
  const u16* Kb = KS + (size_t)bh * 2048 * 128;
  bf16x8 ah[2], al[2];
#pragma unroll
  for (int ks = 0; ks < 2; ++ks){
    const u16* qrow = &Qb[(wave * 16 + lr) * 128];
    ah[ks] = *reinterpret_cast<const bf16x8*>(&qrow[ks * 32 + lk * 8]);
    al[ks] = *reinterpret_cast<const bf16x8*>(&qrow[64 + ks * 32 + lk * 8]);
  }
  f32x4 acc[8] = {};
#pragma unroll
  for (int n = 0; n < 8; ++n){
    const u16* krow = &Kb[(size_t)(k0 + n * 16 + lr) * 128];
    bf16x8 bh0 = *reinterpret_cast<const bf16x8*>(&krow[lk * 8]);
    bf16x8 bh1 = *reinterpret_cast<const bf16x8*>(&krow[32 + lk * 8]);
    bf16x8 bl0 = *reinterpret_cast<const bf16x8*>(&krow[64 + lk * 8]);
    bf16x8 bl1 = *reinterpret_cast<const bf16x8*>(&krow[96 + lk * 8]);
    acc[n] = __builtin_amdgcn_mfma_f32_16x16x32_bf16(ah[0], bh0, acc[n], 0, 0, 0);
    acc[n] = __builtin_amdgcn_mfma_f32_16x16x32_bf16(ah[0], bl0, acc[n], 0, 0, 0);
    acc[n] = __builtin_amdgcn_mfma_f32_16x16x32_bf16(al[0], bh0, acc[n], 0, 0, 0);
    acc[n] = __builtin_amdgcn_mfma_f32_16x16x32_bf16(al[0], bl0, acc[n], 0, 0, 0);
    acc[n] = __builtin_amdgcn_mfma_f32_16x16x32_bf16(ah[1], bh1, acc[n], 0, 0, 0);
    acc[n] = __builtin_amdgcn_mfma_f32_16x16x32_bf16(ah[1], bl1, acc[n], 0, 0, 0);
    acc[n] = __builtin_amdgcn_mfma_f32_16x16x32_bf16(al[1], bh1, acc[n], 0, 0, 0);
    acc[n] = __builtin_amdgcn_mfma_f32_16x16x32_bf16(al[1], bl1, acc[n], 0, 0, 0);
  }
#pragma unroll
  for (int n = 0; n < 8; ++n){
    int k = k0 + n * 16 + lr;
    if (k >= kvlv) continue;
#pragma unroll
    for (int j = 0; j < 4; ++j){
      int i = wave * 16 + lk * 4 + j;
      if (i >= u) continue;
      float s = acc[n][j] * 0.125f;               // / sqrt(64)
      u16 xb = f2bf(s);                           // scores.astype(bf16)
      u16 mb = f2bf(maskp[(size_t)idx_l[i] * 2048 + k]);  // attn_mask.astype(bf16)
      u16 xm = f2bf(bf2f(xb) + bf2f(mb));         // bf16 add
      sc[(size_t)(bh * 64 + i) * 2048 + k] = xm;
    }
  }
}

// ---------- K7: exact bf16 softmax emulation; p written in place ----------
__global__ void softmax_kernel(u16* __restrict__ sc, const int* __restrict__ qvlp,
                               const int* __restrict__ kvlp){
  int bh = blockIdx.y, i = blockIdx.x;
  int u = compute_u(qvlp[0]);
  if (i >= u) return;
  int kvlv = kvlp[0]; if (kvlv > 2048) kvlv = 2048; if (kvlv < 0) kvlv = 0;
  u16* row = sc + (size_t)(bh * 64 + i) * 2048;
  int t = threadIdx.x;
  float x[8];
  float lm = -3.4e38f;
#pragma unroll
  for (int j = 0; j < 8; ++j){
    int k = t + j * 256;
    x[j] = (k < kvlv) ? bf2f(row[k]) : -3.4e38f;
    lm = fmaxf(lm, x[j]);
  }
  __shared__ float red[256];
  red[t] = lm; __syncthreads();
  for (int s = 128; s > 0; s >>= 1){ if (t < s) red[t] = fmaxf(red[t], red[t+s]); __syncthreads(); }
  float m = red[0];
  __syncthreads();
  float e[8]; float ls = 0.f;
#pragma unroll
  for (int j = 0; j < 8; ++j){
    int k = t + j * 256;
    if (k < kvlv){
      u16 ub = f2bf(x[j] - m);            // bf16 subtract
      u16 eb = f2bf(expf(bf2f(ub)));      // bf16 exp
      e[j] = bf2f(eb);
      ls += e[j];
    } else e[j] = 0.f;
  }
  red[t] = ls; __syncthreads();
  for (int s = 128; s > 0; s >>= 1){ if (t < s) red[t] += red[t+s]; __syncthreads(); }
  float S = red[0];                       // f32 accumulation (jnp.sum upcast)
  float Sb = bf2f(f2bf(S));               // downcast back to bf16
#pragma unroll
  for (int j = 0; j < 8; ++j){
    int k = t + j * 256;
    if (k < 2048) row[k] = (k < kvlv) ? f2bf(e[j] / Sb) : (u16)0;   // bf16 divide
  }
}

// ---------- K8a: PV via MFMA, no LDS. part[kc][bh][64 rows][64 d] ----------
__global__ void pv_mfma(const u16* __restrict__ probs, const u16* __restrict__ VT,
                        float* __restrict__ part, const int* __restrict__ kvlp)
{
  int bh = blockIdx.y; int b = bh >> 4, h = bh & 15;
  int kvlv = kvlp[0]; if (kvlv > 2048) kvlv = 2048; if (kvlv < 0) kvlv = 0;
  int kc = blockIdx.x;
  int k0 = kc * 128;
  if (k0 >= kvlv) return;
  int t = threadIdx.x, w = t >> 6, lane = t & 63;
  int lr = lane & 15, lk = lane >> 4;
  const u16* Pb = probs + (size_t)bh * 64 * 2048;
  const u16* Vb = VT + (size_t)(b * 16 + h) * 128 * 2048;
  f32x4 acc[4] = {};
#pragma unroll
  for (int ks = 0; ks < 4; ++ks){
    int kk = k0 + ks * 32 + lk * 8;
    bf16x8 A0 = *reinterpret_cast<const bf16x8*>(Pb + (size_t)(lr     ) * 2048 + kk);
    bf16x8 A1 = *reinterpret_cast<const bf16x8*>(Pb + (size_t)(lr + 16) * 2048 + kk);
    bf16x8 A2 = *reinterpret_cast<const bf16x8*>(Pb + (size_t)(lr + 32) * 2048 + kk);
    bf16x8 A3 = *reinterpret_cast<const bf16x8*>(Pb + (size_t)(lr + 48) * 2048 + kk);
    bf16x8 Bh = *reinterpret_cast<const bf16x8*>(Vb + (size_t)(w * 16 + lr     ) * 2048 + kk);
    bf16x8 Bl = *reinterpret_cast<const bf16x8*>(Vb + (size_t)(w * 16 + lr + 64) * 2048 + kk);
    acc[0] = __builtin_amdgcn_mfma_f32_16x16x32_bf16(A0, Bh, acc[0], 0, 0, 0);
    acc[1] = __builtin_amdgcn_mfma_f32_16x16x32_bf16(A1, Bh, acc[1], 0, 0, 0);
    acc[2] = __builtin_amdgcn_mfma_f32_16x16x32_bf16(A2, Bh, acc[2], 0, 0, 0);
    acc[3] = __builtin_amdgcn_mfma_f32_16x16x32_bf16(A3, Bh, acc[3], 0, 0, 0);
    acc[0] = __builtin_amdgcn_mfma_f32_16x16x32_bf16(A0, Bl, acc[0], 0, 0, 0);
    acc[1] = __builtin_amdgcn_mfma_f32_16x16x32_bf16(A1, Bl, acc[1], 0, 0, 0);
    acc[2] = __builtin_amdgcn_mfma_f32_16x16x32_bf16(A2, Bl, acc[2], 0, 0, 0);
    acc[3] = __builtin_amdgcn_mfma_f32_16x16x32_bf16(A3, Bl, acc[3], 0, 0, 0);
  }
  float* pc = part + (size_t)(kc * 32 + bh) * 64 * 64;
#pragma unroll
  for (int m = 0; m < 4; ++m){
    int row = m * 16 + lk * 4;
#pragma unroll
    for (int j = 0; j < 4; ++j)
      pc[(size_t)(row + j) * 64 + w * 16 + lr] = acc[m][j];
  }
}

// ---------- K8b: deterministic reduction of PV partials (R3-R10 validated) ----------
__global__ void pv_reduce(const float* __restrict__ part, float* __restrict__ ctx,
                          const int* __restrict__ qvlp, const int* __restrict__ kvlp){
  int bh = blockIdx.y, r = blockIdx.x;
  int u = compute_u(qvlp[0]);
  if (r >= u) return;
  int kvlv = kvlp[0]; if (kvlv > 2048) kvlv = 2048; if (kvlv < 0) kvlv = 0;
  int kcmax = (kvlv + 127) / 128;
  int d = threadIdx.x;   // 64
  float s = 0.f;
  for (int kc = 0; kc < kcmax; ++kc)
    s += part[(size_t)((kc * 32 + bh) * 64 + r) * 64 + d];
  ctx[(size_t)(bh * 64 + r) * 64 + d] = s;
}

// ---------- K9a: OH[bh][64][cols] = ctx(64x64) @ Wo_h^T slice, MFMA 3-term ----------
// grid (16 cs, 32 bh); each wave owns ONE col-frag (cg = cs*4 + wave).
// R14-validated math/layout; only the work decomposition differs.
__global__ __launch_bounds__(256) void oh_mfma2(
    const float* __restrict__ ctx, const u16* __restrict__ WO1,
    const u16* __restrict__ WO2, float* __restrict__ OH,
    const int* __restrict__ qvlp)
{
  int cs = blockIdx.x;                  // 0..15
  int bh = blockIdx.y; int h = bh & 15;
  int t = threadIdx.x;
  int u = compute_u(qvlp[0]);
  __shared__ __align__(16) u16 CT[64 * 128];   // ctx split-bf16 [64 rows][hi|lo]
  for (int e = t; e < 4096; e += 256){
    int i = e >> 6, d = e & 63;
    float s = (i < u) ? ctx[(size_t)(bh * 64 + i) * 64 + d] : 0.f;
    u16 hi = f2bf(s);
    CT[i * 128 + d] = hi;
    CT[i * 128 + 64 + d] = f2bf(s - bf2f(hi));
  }
  __syncthreads();
  int wave = t >> 6, lane = t & 63;
  int lr = lane & 15, lk = lane >> 4;
  bf16x8 ah[4][2], al[4][2];
#pragma unroll
  for (int m = 0; m < 4; ++m){
    const u16* crow = &CT[(m * 16 + lr) * 128];
#pragma unroll
    for (int ks = 0; ks < 2; ++ks){
      ah[m][ks] = *reinterpret_cast<const bf16x8*>(&crow[ks * 32 + lk * 8]);
      al[m][ks] = *reinterpret_cast<const bf16x8*>(&crow[64 + ks * 32 + lk * 8]);
    }
  }
  int c = cs * 4 + wave;                // col-frag 0..63 (16 cols each)
  const u16* w1r = &WO1[(size_t)(c * 16 + lr) * 1024 + h * 64];
  const u16* w2r = &WO2[(size_t)(c * 16 + lr) * 1024 + h * 64];
  bf16x8 bh0 = *reinterpret_cast<const bf16x8*>(&w1r[lk * 8]);
  bf16x8 bh1 = *reinterpret_cast<const bf16x8*>(&w1r[32 + lk * 8]);
  bf16x8 bl0 = *reinterpret_cast<const bf16x8*>(&w2r[lk * 8]);
  bf16x8 bl1 = *reinterpret_cast<const bf16x8*>(&w2r[32 + lk * 8]);
  float* ohb = OH + (size_t)bh * 64 * 1024;
  f32x4 acc[4] = {};
#pragma unroll
  for (int m = 0; m < 4; ++m){
    acc[m] = __builtin_amdgcn_mfma_f32_16x16x32_bf16(ah[m][0], bh0, acc[m], 0, 0, 0);
    acc[m] = __builtin_amdgcn_mfma_f32_16x16x32_bf16(ah[m][1], bh1, acc[m], 0, 0, 0);
    acc[m] = __builtin_amdgcn_mfma_f32_16x16x32_bf16(ah[m][0], bl0, acc[m], 0, 0, 0);
    acc[m] = __builtin_amdgcn_mfma_f32_16x16x32_bf16(ah[m][1], bl1, acc[m], 0, 0, 0);
    acc[m] = __builtin_amdgcn_mfma_f32_16x16x32_bf16(al[m][0], bh0, acc[m], 0, 0, 0);
    acc[m] = __builtin_amdgcn_mfma_f32_16x16x32_bf16(al[m][1], bh1, acc[m], 0, 0, 0);
#pragma unroll
    for (int j = 0; j < 4; ++j)
      ohb[(size_t)(m * 16 + lk * 4 + j) * 1024 + c * 16 + lr] = acc[m][j];
  }
}

// ---------- K9b: out = bo + sum_{h in hmask} OH[bh][seli] (R14 validated) ----------
__global__ __launch_bounds__(256) void out_assemble(
    const float* __restrict__ OH, const float* __restrict__ bo,
    const unsigned int* __restrict__ hmask, const unsigned char* __restrict__ seli,
    float* __restrict__ out)
{
  int row = blockIdx.x;                 // b*2048 + l
  int b = row >> 11, l = row & 2047;
  int t = threadIdx.x;
  float acc[4];
#pragma unroll
  for (int r = 0; r < 4; ++r) acc[r] = bo[t + r * 256];
  unsigned int m = hmask[row];
  while (m){
    int h = __ffs(m) - 1; m &= (m - 1);
    int bh = b * 16 + h;
    int i = (int)seli[(size_t)bh * 2048 + l];
    const float* orow = OH + ((size_t)bh * 64 + i) * 1024;
#pragma unroll
    for (int r = 0; r < 4; ++r) acc[r] += orow[t + r * 256];
  }
  float* dst = out + (size_t)row * 1024;
#pragma unroll
  for (int r = 0; r < 4; ++r) dst[t + r * 256] = acc[r];
}

__global__ void fail_fill(float* o, int n){
  int i = blockIdx.x * 256 + threadIdx.x;
  if (i < n) o[i] = 12345.0f;
}

// ---------------------------------------------------------------------------
extern "C" void kernel_launch(void* const* d_in, const int* in_sizes, int n_in,
                              void* d_out, int out_size, void* d_ws, size_t ws_size,
                              hipStream_t stream)
{
  const float* query = (const float*)d_in[0];
  const float* key   = (const float*)d_in[1];
  const float* value = (const float*)d_in[2];
  const float* maskp = (const float*)d_in[3];
  const float* Wq = (const float*)d_in[4];
  const float* bq = (const float*)d_in[5];
  const float* Wk = (const float*)d_in[6];
  const float* bk = (const float*)d_in[7];
  const float* Wv = (const float*)d_in[8];
  const float* bv = (const float*)d_in[9];
  const float* Wo = (const float*)d_in[10];
  const float* bo = (const float*)d_in[11];
  const int* qvl = (const int*)d_in[12];
  const int* kvl = (const int*)d_in[13];
  float* out = (float*)d_out;

  char* ws = (char*)d_ws;
  size_t off = 0;
  auto alloc = [&](size_t bytes) -> void* {
    void* p = ws + off;
    off = (off + bytes + 255) & ~(size_t)255;
    return p;
  };
  u16* X1 = (u16*)alloc(3ull * 4194304 * 2);
  u16* X2 = (u16*)alloc(3ull * 4194304 * 2);
  u16* W1 = (u16*)alloc(3ull * 1048576 * 2);
  u16* W2 = (u16*)alloc(3ull * 1048576 * 2);
  u16* WO1 = (u16*)alloc(1048576ull * 2);
  u16* WO2 = (u16*)alloc(1048576ull * 2);
  float* PROJ = (float*)alloc(3ull * 4194304 * 4);
  float* QN   = (float*)alloc(2ull * 16 * 2048 * 4);
  int*   TOPK = (int*)alloc(2ull * 16 * 64 * 4);
  unsigned char* SELI = (unsigned char*)alloc(2ull * 16 * 2048);
  unsigned int* HMASK = (unsigned int*)alloc(2ull * 2048 * 4);
  u16*   SC   = (u16*)alloc(2048ull * 2048 * 2);
  u16*   QS   = (u16*)alloc(32ull * 64 * 128 * 2);
  float* CTX  = (float*)alloc(32ull * 64 * 64 * 4);
  float* OH   = (float*)alloc(32ull * 64 * 1024 * 4);

  // KS (split-bf16 K) aliases the PROJ z==1 slice (exactly 16.78 MB)
  u16* KS = (u16*)(PROJ + 1ull * 4194304);
  // VT (split-bf16 transposed V) aliases the PROJ z==2 slice (exactly 16.78 MB)
  u16* VT = (u16*)(PROJ + 2ull * 4194304);
  // PV partials alias X1 (24 MB, dead after gemm_proj): 16*32*64*64*4 = 8.4 MB
  float* PART = (float*)X1;

  if (ws_size < off){
    fail_fill<<<(out_size + 255) / 256, 256, 0, stream>>>(out, out_size);
    return;
  }

  expand_kernel<<<8192, 256, 0, stream>>>(query, key, value, Wq, Wk, Wv, Wo,
                                          X1, X2, W1, W2, WO1, WO2, HMASK);
  gemm_proj<<<dim3(8, 16, 3), 512, 0, stream>>>(X1, X2, W1, W2, bq, bk, bv, PROJ, QN);
  topk_kernel<<<32, 256, 0, stream>>>(QN, TOPK, SELI, HMASK, PROJ, QS, qvl);
  scores_mfma<<<dim3(16, 32), 256, 0, stream>>>(QS, KS, TOPK, maskp, SC, qvl, kvl);
  softmax_kernel<<<dim3(64, 32), 256, 0, stream>>>(SC, qvl, kvl);
  pv_mfma<<<dim3(16, 32), 256, 0, stream>>>(SC, VT, PART, kvl);
  pv_reduce<<<dim3(64, 32), 64, 0, stream>>>(PART, CTX, qvl, kvl);
  oh_mfma2<<<dim3(16, 32), 256, 0, stream>>>(CTX, WO1, WO2, OH, qvl);
  out_assemble<<<4096, 256, 0, stream>>>(OH, bo, HMASK, SELI, out);
}

// Round 19
// 211.100 us; speedup vs baseline: 1.5342x; 1.0486x over previous
//
#include <hip/hip_runtime.h>

typedef unsigned short u16;
typedef __bf16 bf16x8 __attribute__((ext_vector_type(8)));
typedef float f32x4 __attribute__((ext_vector_type(4)));

// ---------- numeric helpers (RNE f32<->bf16, matching XLA/ml_dtypes) ----------
__device__ __forceinline__ u16 f2bf(float f){
  unsigned int x = __float_as_uint(f);
  unsigned int r = (x + 0x7FFFu + ((x >> 16) & 1u)) >> 16;
  return (u16)r;
}
__device__ __forceinline__ float bf2f(u16 u){
  return __uint_as_float(((unsigned int)u) << 16);
}
__device__ __forceinline__ int compute_u(int qvlv){
  int mm = qvlv > 2 ? qvlv : 2;
  int u = (int)(5.0 * log((double)mm));   // FACTOR=5.0, python int() truncation
  if (u < 1) u = 1;
  if (u > 64) u = 64;
  return u;
}
__device__ __forceinline__ void gload_lds16(const void* g, void* l){
  __builtin_amdgcn_global_load_lds(
      (const __attribute__((address_space(1))) void*)g,
      (__attribute__((address_space(3))) void*)l, 16, 0, 0);
}

// ---------- K1: split f32 -> 2 bf16 levels (16B stores); X: q/k/v, W: Wq/Wk/Wv/Wo ----------
// 8192 blocks exactly (X 1572864 groups + W 524288 groups, 8 floats/group).
// Also zeroes hmask.
__global__ void expand_kernel(const float* __restrict__ xq, const float* __restrict__ xk,
                              const float* __restrict__ xv,
                              const float* __restrict__ wq, const float* __restrict__ wk,
                              const float* __restrict__ wv, const float* __restrict__ wo,
                              u16* __restrict__ X1, u16* __restrict__ X2,
                              u16* __restrict__ W1, u16* __restrict__ W2,
                              u16* __restrict__ WO1, u16* __restrict__ WO2,
                              unsigned int* __restrict__ hmask)
{
  int t = threadIdx.x;
  size_t g = (size_t)blockIdx.x * 256 + t;      // one group = 8 floats
  if (g < 4096) hmask[g] = 0;
  const float* src; u16 *d1, *d2;
  if (g < 1572864ull) {                 // X part: 3 * 4194304 / 8
    int p = (int)(g >> 19);
    size_t e = (g & 524287ull) * 8;
    src = (p == 0 ? xq : (p == 1 ? xk : xv)) + e;
    size_t o = (size_t)p * 4194304ull + e;
    d1 = X1 + o; d2 = X2 + o;
  } else {                              // W part: 4 * 1048576 / 8
    size_t wg = g - 1572864ull;
    int p = (int)(wg >> 17);
    size_t e = (wg & 131071ull) * 8;
    src = (p == 0 ? wq : (p == 1 ? wk : (p == 2 ? wv : wo))) + e;
    if (p < 3){
      size_t o = (size_t)p * 1048576ull + e;
      d1 = W1 + o; d2 = W2 + o;
    } else {
      d1 = WO1 + e; d2 = WO2 + e;
    }
  }
  float4 a = *reinterpret_cast<const float4*>(src);
  float4 b = *reinterpret_cast<const float4*>(src + 4);
  float xs[8] = {a.x, a.y, a.z, a.w, b.x, b.y, b.z, b.w};
  unsigned int hw[4], lw[4];
#pragma unroll
  for (int i = 0; i < 4; ++i){
    u16 h0 = f2bf(xs[2*i]);     u16 l0 = f2bf(xs[2*i]     - bf2f(h0));
    u16 h1 = f2bf(xs[2*i + 1]); u16 l1 = f2bf(xs[2*i + 1] - bf2f(h1));
    hw[i] = (unsigned int)h0 | ((unsigned int)h1 << 16);
    lw[i] = (unsigned int)l0 | ((unsigned int)l1 << 16);
  }
  *reinterpret_cast<uint4*>(d1) = make_uint4(hw[0], hw[1], hw[2], hw[3]);
  *reinterpret_cast<uint4*>(d2) = make_uint4(lw[0], lw[1], lw[2], lw[3]);
}

// ---------- K3: split-precision bf16 MFMA GEMM  C = X @ W^T + bias ----------
// R10/R18 schedule (frozen), BM=128 / 4 waves (2x2, wave-tile 64x64 unchanged),
// set=32KB, dbuf=64KB -> 2 blocks/CU (m114 inter-block overlap). Term order and
// per-output accumulation bit-identical to R18.
// z=0: Q -> f32 PROJ + qn; z=1: K -> KS split-bf16; z=2: V -> VT split-bf16 T.
__global__ __launch_bounds__(256, 2) void gemm_proj(
    const u16* __restrict__ X1, const u16* __restrict__ X2,
    const u16* __restrict__ W1, const u16* __restrict__ W2,
    const float* __restrict__ bq, const float* __restrict__ bk, const float* __restrict__ bv,
    float* __restrict__ PROJ, float* __restrict__ qn)
{
  int z = blockIdx.z;
  // XCD-chunked bijective swizzle: 256 blocks/z, 8 XCDs, 32 per XCD
  int orig = blockIdx.x + blockIdx.y * 8;          // 0..255
  int wgid = (orig & 7) * 32 + (orig >> 3);
  int bx = wgid & 7, by = wgid >> 3;               // bx<8, by<32

  const u16* Xa0 = X1 + (size_t)z * 4194304;
  const u16* Xa1 = X2 + (size_t)z * 4194304;
  const u16* Wb0 = W1 + (size_t)z * 1048576;
  const u16* Wb1 = W2 + (size_t)z * 1048576;
  const float* bias = (z == 0) ? bq : (z == 1 ? bk : bv);
  float* C = PROJ + (size_t)z * 4194304;

  // set: A0[128x32]@0, A1@4096, B0[128x32]@8192, B1@12288 (16384 u16 = 32KB)
  __shared__ __align__(16) u16 T[2 * 16384];       // 64 KB
  u16* SET0 = T;
  u16* SET1 = T + 16384;

  int t = threadIdx.x;
  int wave = t >> 6, lane = t & 63;
  int wm = wave >> 1, wn = wave & 1;               // 2 x 2 wave grid
  int lr = lane & 15, lk = lane >> 4;
  int rowA = by * 128, rowB = bx * 128;
  f32x4 acc[4][4] = {};
  bf16x8 afA[4], afB[4], bgA[4], bgB[4];

#define STAGET(dstbase, G, R0)                                                \
  {                                                                           \
    _Pragma("unroll")                                                         \
    for (int i = 0; i < 2; ++i){                                              \
      int p = i * 256 + t;                                                    \
      int r = p >> 2;                                                         \
      int c = (p & 3) ^ ((r >> 1) & 3);                                       \
      gload_lds16(G + (size_t)(R0 + r) * 1024 + pk + c * 8,                   \
                  (dstbase) + p * 8);                                         \
    }                                                                         \
  }
#define STAGE_SET(S)                                                          \
  {                                                                           \
    STAGET((S), Xa0, rowA); STAGET((S) + 4096, Xa1, rowA);                    \
    STAGET((S) + 8192, Wb0, rowB); STAGET((S) + 12288, Wb1, rowB);            \
  }
#define LOADA(dst, tile)                                                      \
  {                                                                           \
    _Pragma("unroll")                                                         \
    for (int m = 0; m < 4; ++m){                                              \
      int r = wm * 64 + m * 16 + lr;                                          \
      dst[m] = *reinterpret_cast<const bf16x8*>(                              \
          &(tile)[r * 32 + ((lk ^ ((r >> 1) & 3)) << 3)]);                    \
    }                                                                         \
  }
#define LOADB(dst, tile)                                                      \
  {                                                                           \
    _Pragma("unroll")                                                         \
    for (int n = 0; n < 4; ++n){                                              \
      int r = wn * 64 + n * 16 + lr;                                          \
      dst[n] = *reinterpret_cast<const bf16x8*>(                              \
          &(tile)[r * 32 + ((lk ^ ((r >> 1) & 3)) << 3)]);                    \
    }                                                                         \
  }
#define GRPX(A_, B_)                                                          \
  {                                                                           \
    __builtin_amdgcn_s_setprio(1);                                            \
    _Pragma("unroll")                                                         \
    for (int m = 0; m < 4; ++m)                                               \
      _Pragma("unroll")                                                       \
      for (int n = 0; n < 4; ++n)                                             \
        acc[m][n] = __builtin_amdgcn_mfma_f32_16x16x32_bf16(A_[m], B_[n],     \
                                                            acc[m][n], 0,0,0);\
    __builtin_amdgcn_s_setprio(0);                                            \
  }

  {                                    // prologue: stage chunk 0
    int pk = 0;
    STAGE_SET(SET0);
  }
  __syncthreads();

  for (int kt = 0; kt < 32; ++kt){
    u16* CUR = (kt & 1) ? SET1 : SET0;
    u16* NXT = (kt & 1) ? SET0 : SET1;
    if (kt < 31){
      int pk = (kt + 1) * 32;
      STAGE_SET(NXT);                  // issue next-chunk loads (hidden under MFMA)
    }
    __builtin_amdgcn_sched_barrier(0); // keep stage-issue ahead of compute
    u16* A0t = CUR;         u16* A1t = CUR + 4096;
    u16* B0t = CUR + 8192;  u16* B1t = CUR + 12288;
    LOADA(afA, A0t); LOADB(bgA, B0t);
    LOADB(bgB, B1t); GRPX(afA, bgA);   // A0*B0
    LOADA(afB, A1t); GRPX(afA, bgB);   // A0*B1
                     GRPX(afB, bgA);   // A1*B0
    __syncthreads();                   // drains vmcnt: next chunk staged & visible
  }
#undef STAGET
#undef STAGE_SET
#undef LOADA
#undef LOADB
#undef GRPX

  if (z == 0){
    float sq[4][4] = {};                      // [m][j] partial row-norms
#pragma unroll
    for (int m = 0; m < 4; ++m){
      int row0 = by * 128 + wm * 64 + m * 16 + lk * 4;
#pragma unroll
      for (int n = 0; n < 4; ++n){
        int col = bx * 128 + wn * 64 + n * 16 + lr;
        float bb = bias[col];
#pragma unroll
        for (int j = 0; j < 4; ++j){
          float v = acc[m][n][j] + bb;
          C[(size_t)(row0 + j) * 1024 + col] = v;
          sq[m][j] += v * v;
        }
      }
    }
    int hh = bx * 2 + wn;                     // this (bx,wn) covers head hh fully
#pragma unroll
    for (int m = 0; m < 4; ++m){
#pragma unroll
      for (int j = 0; j < 4; ++j){
        float s = sq[m][j];
        s += __shfl_xor(s, 1);
        s += __shfl_xor(s, 2);
        s += __shfl_xor(s, 4);
        s += __shfl_xor(s, 8);
        if (lr == 0){
          int row = by * 128 + wm * 64 + m * 16 + lk * 4 + j;
          qn[(size_t)((row >> 11) * 16 + hh) * 2048 + (row & 2047)] = s;
        }
      }
    }
  } else if (z == 1){
    u16* KS = (u16*)C;   // [32][2048][128] u16 (hi|lo planes)
#pragma unroll
    for (int m = 0; m < 4; ++m){
      int r0 = by * 128 + wm * 64 + m * 16 + lk * 4;
      int b = r0 >> 11, kb = r0 & 2047;
#pragma unroll
      for (int n = 0; n < 4; ++n){
        int c = bx * 128 + wn * 64 + n * 16 + lr;
        float bb = bias[c];
        int h = c >> 6, d = c & 63;
#pragma unroll
        for (int j = 0; j < 4; ++j){
          float v = acc[m][n][j] + bb;
          u16 hi = f2bf(v);
          u16 lo = f2bf(v - bf2f(hi));
          size_t base = ((size_t)(b * 16 + h) * 2048 + (size_t)(kb + j)) * 128;
          KS[base + d] = hi;
          KS[base + 64 + d] = lo;
        }
      }
    }
  } else {
    u16* VT = (u16*)C;   // [32][128][2048] u16
#pragma unroll
    for (int m = 0; m < 4; ++m){
      int r0 = by * 128 + wm * 64 + m * 16 + lk * 4;
      int b = r0 >> 11, kb = r0 & 2047;
#pragma unroll
      for (int n = 0; n < 4; ++n){
        int c = bx * 128 + wn * 64 + n * 16 + lr;
        float bb = bias[c];
        int h = c >> 6, d = c & 63;
        u16 hi[4], lo[4];
#pragma unroll
        for (int j = 0; j < 4; ++j){
          float v = acc[m][n][j] + bb;
          hi[j] = f2bf(v);
          lo[j] = f2bf(v - bf2f(hi[j]));
        }
        size_t base = ((size_t)(b * 16 + h) * 128) * 2048 + (size_t)kb;
        *reinterpret_cast<ushort4*>(&VT[base + (size_t)d * 2048]) =
            make_ushort4(hi[0], hi[1], hi[2], hi[3]);
        *reinterpret_cast<ushort4*>(&VT[base + (size_t)(64 + d) * 2048]) =
            make_ushort4(lo[0], lo[1], lo[2], lo[3]);
      }
    }
  }
}

// ---------- K5: top-u per (b,h): 1-wave barrier-free selection + QS gather ----------
__global__ __launch_bounds__(256) void topk_kernel(
    const float* __restrict__ qn, int* __restrict__ topk,
    unsigned char* __restrict__ seli, unsigned int* __restrict__ hmask,
    const float* __restrict__ PROJ, u16* __restrict__ QS,
    const int* __restrict__ qvlp){
  int bh = blockIdx.x; int b = bh >> 4, h = bh & 15;
  int u = compute_u(qvlp[0]);
  int t = threadIdx.x;
  __shared__ int sidx_l[64];
  if (t < 64){                              // wave 0 only: selection
    int lane = t;
    float v[32];
#pragma unroll
    for (int j = 0; j < 32; ++j) v[j] = qn[(size_t)bh * 2048 + j * 64 + lane];
    for (int it = 0; it < u; ++it){
      float bv = v[0]; int bi = lane;
#pragma unroll
      for (int j = 1; j < 32; ++j){
        if (v[j] > bv){ bv = v[j]; bi = j * 64 + lane; }   // strict >: lowest j
      }
#pragma unroll
      for (int off = 1; off < 64; off <<= 1){
        float ov = __shfl_xor(bv, off);
        int   oi = __shfl_xor(bi, off);
        if (ov > bv || (ov == bv && oi < bi)){ bv = ov; bi = oi; }
      }
      if (lane == 0){
        topk[bh * 64 + it] = bi;
        seli[(size_t)bh * 2048 + bi] = (unsigned char)it;
        atomicOr(&hmask[b * 2048 + bi], 1u << h);
        sidx_l[it] = bi;
      }
#pragma unroll
      for (int j = 0; j < 32; ++j)          // static-index suppression
        if (j * 64 + lane == bi) v[j] = -3.4e38f;
    }
  }
  __syncthreads();
  for (int e = t; e < 64 * 64; e += 256){   // gather phase: all 256 threads
    int i = e >> 6, d = e & 63;
    float v = 0.f;
    if (i < u) v = PROJ[(size_t)(b * 2048 + sidx_l[i]) * 1024 + h * 64 + d];
    u16 hi = f2bf(v);
    u16 lo = f2bf(v - bf2f(hi));
    QS[(size_t)bh * 8192 + i * 128 + d] = hi;
    QS[(size_t)bh * 8192 + i * 128 + 64 + d] = lo;
  }
}

// ---------- K6b: scores via MFMA: S = Q_sel @ K^T, bf16 round + bf16 mask add ----------
__global__ __launch_bounds__(256) void scores_mfma(
    const u16* __restrict__ QS, const u16* __restrict__ KS,
    const int* __restrict__ topk, const float* __restrict__ maskp,
    u16* __restrict__ sc, const int* __restrict__ qvlp, const int* __restrict__ kvlp)
{
  int bh = blockIdx.y;
  int kvlv = kvlp[0]; if (kvlv > 2048) kvlv = 2048; if (kvlv < 0) kvlv = 0;
  int u = compute_u(qvlp[0]);
  int k0 = blockIdx.x * 128;
  if (k0 >= kvlv) return;
  int t = threadIdx.x, wave = t >> 6, lane = t & 63;
  int lr = lane & 15, lk = lane >> 4;
  __shared__ int idx_l[64];
  if (t < 64) idx_l[t] = (t < u) ? topk[bh * 64 + t] : 0;
  __syncthreads();
  const u16* Qb = QS + (size_t)bh * 8192;
  const u16* Kb = KS + (size_t)bh * 2048 * 128;
  bf16x8 ah[2], al[2];
#pragma unroll
  for (int ks = 0; ks < 2; ++ks){
    const u16* qrow = &Qb[(wave * 16 + lr) * 128];
    ah[ks] = *reinterpret_cast<const bf16x8*>(&qrow[ks * 32 + lk * 8]);
    al[ks] = *reinterpret_cast<const bf16x8*>(&qrow[64 + ks * 32 + lk * 8]);
  }
  f32x4 acc[8] = {};
#pragma unroll
  for (int n = 0; n < 8; ++n){
    const u16* krow = &Kb[(size_t)(k0 + n * 16 + lr) * 128];
    bf16x8 bh0 = *reinterpret_cast<const bf16x8*>(&krow[lk * 8]);
    bf16x8 bh1 = *reinterpret_cast<const bf16x8*>(&krow[32 + lk * 8]);
    bf16x8 bl0 = *reinterpret_cast<const bf16x8*>(&krow[64 + lk * 8]);
    bf16x8 bl1 = *reinterpret_cast<const bf16x8*>(&krow[96 + lk * 8]);
    acc[n] = __builtin_amdgcn_mfma_f32_16x16x32_bf16(ah[0], bh0, acc[n], 0, 0, 0);
    acc[n] = __builtin_amdgcn_mfma_f32_16x16x32_bf16(ah[0], bl0, acc[n], 0, 0, 0);
    acc[n] = __builtin_amdgcn_mfma_f32_16x16x32_bf16(al[0], bh0, acc[n], 0, 0, 0);
    acc[n] = __builtin_amdgcn_mfma_f32_16x16x32_bf16(al[0], bl0, acc[n], 0, 0, 0);
    acc[n] = __builtin_amdgcn_mfma_f32_16x16x32_bf16(ah[1], bh1, acc[n], 0, 0, 0);
    acc[n] = __builtin_amdgcn_mfma_f32_16x16x32_bf16(ah[1], bl1, acc[n], 0, 0, 0);
    acc[n] = __builtin_amdgcn_mfma_f32_16x16x32_bf16(al[1], bh1, acc[n], 0, 0, 0);
    acc[n] = __builtin_amdgcn_mfma_f32_16x16x32_bf16(al[1], bl1, acc[n], 0, 0, 0);
  }
#pragma unroll
  for (int n = 0; n < 8; ++n){
    int k = k0 + n * 16 + lr;
    if (k >= kvlv) continue;
#pragma unroll
    for (int j = 0; j < 4; ++j){
      int i = wave * 16 + lk * 4 + j;
      if (i >= u) continue;
      float s = acc[n][j] * 0.125f;               // / sqrt(64)
      u16 xb = f2bf(s);                           // scores.astype(bf16)
      u16 mb = f2bf(maskp[(size_t)idx_l[i] * 2048 + k]);  // attn_mask.astype(bf16)
      u16 xm = f2bf(bf2f(xb) + bf2f(mb));         // bf16 add
      sc[(size_t)(bh * 64 + i) * 2048 + k] = xm;
    }
  }
}

// ---------- K7: exact bf16 softmax emulation; p written in place ----------
__global__ void softmax_kernel(u16* __restrict__ sc, const int* __restrict__ qvlp,
                               const int* __restrict__ kvlp){
  int bh = blockIdx.y, i = blockIdx.x;
  int u = compute_u(qvlp[0]);
  if (i >= u) return;
  int kvlv = kvlp[0]; if (kvlv > 2048) kvlv = 2048; if (kvlv < 0) kvlv = 0;
  u16* row = sc + (size_t)(bh * 64 + i) * 2048;
  int t = threadIdx.x;
  float x[8];
  float lm = -3.4e38f;
#pragma unroll
  for (int j = 0; j < 8; ++j){
    int k = t + j * 256;
    x[j] = (k < kvlv) ? bf2f(row[k]) : -3.4e38f;
    lm = fmaxf(lm, x[j]);
  }
  __shared__ float red[256];
  red[t] = lm; __syncthreads();
  for (int s = 128; s > 0; s >>= 1){ if (t < s) red[t] = fmaxf(red[t], red[t+s]); __syncthreads(); }
  float m = red[0];
  __syncthreads();
  float e[8]; float ls = 0.f;
#pragma unroll
  for (int j = 0; j < 8; ++j){
    int k = t + j * 256;
    if (k < kvlv){
      u16 ub = f2bf(x[j] - m);            // bf16 subtract
      u16 eb = f2bf(expf(bf2f(ub)));      // bf16 exp
      e[j] = bf2f(eb);
      ls += e[j];
    } else e[j] = 0.f;
  }
  red[t] = ls; __syncthreads();
  for (int s = 128; s > 0; s >>= 1){ if (t < s) red[t] += red[t+s]; __syncthreads(); }
  float S = red[0];                       // f32 accumulation (jnp.sum upcast)
  float Sb = bf2f(f2bf(S));               // downcast back to bf16
#pragma unroll
  for (int j = 0; j < 8; ++j){
    int k = t + j * 256;
    if (k < 2048) row[k] = (k < kvlv) ? f2bf(e[j] / Sb) : (u16)0;   // bf16 divide
  }
}

// ---------- K8a: PV via MFMA, no LDS. part[kc][bh][64 rows][64 d] ----------
__global__ void pv_mfma(const u16* __restrict__ probs, const u16* __restrict__ VT,
                        float* __restrict__ part, const int* __restrict__ kvlp)
{
  int bh = blockIdx.y; int b = bh >> 4, h = bh & 15;
  int kvlv = kvlp[0]; if (kvlv > 2048) kvlv = 2048; if (kvlv < 0) kvlv = 0;
  int kc = blockIdx.x;
  int k0 = kc * 128;
  if (k0 >= kvlv) return;
  int t = threadIdx.x, w = t >> 6, lane = t & 63;
  int lr = lane & 15, lk = lane >> 4;
  const u16* Pb = probs + (size_t)bh * 64 * 2048;
  const u16* Vb = VT + (size_t)(b * 16 + h) * 128 * 2048;
  f32x4 acc[4] = {};
#pragma unroll
  for (int ks = 0; ks < 4; ++ks){
    int kk = k0 + ks * 32 + lk * 8;
    bf16x8 A0 = *reinterpret_cast<const bf16x8*>(Pb + (size_t)(lr     ) * 2048 + kk);
    bf16x8 A1 = *reinterpret_cast<const bf16x8*>(Pb + (size_t)(lr + 16) * 2048 + kk);
    bf16x8 A2 = *reinterpret_cast<const bf16x8*>(Pb + (size_t)(lr + 32) * 2048 + kk);
    bf16x8 A3 = *reinterpret_cast<const bf16x8*>(Pb + (size_t)(lr + 48) * 2048 + kk);
    bf16x8 Bh = *reinterpret_cast<const bf16x8*>(Vb + (size_t)(w * 16 + lr     ) * 2048 + kk);
    bf16x8 Bl = *reinterpret_cast<const bf16x8*>(Vb + (size_t)(w * 16 + lr + 64) * 2048 + kk);
    acc[0] = __builtin_amdgcn_mfma_f32_16x16x32_bf16(A0, Bh, acc[0], 0, 0, 0);
    acc[1] = __builtin_amdgcn_mfma_f32_16x16x32_bf16(A1, Bh, acc[1], 0, 0, 0);
    acc[2] = __builtin_amdgcn_mfma_f32_16x16x32_bf16(A2, Bh, acc[2], 0, 0, 0);
    acc[3] = __builtin_amdgcn_mfma_f32_16x16x32_bf16(A3, Bh, acc[3], 0, 0, 0);
    acc[0] = __builtin_amdgcn_mfma_f32_16x16x32_bf16(A0, Bl, acc[0], 0, 0, 0);
    acc[1] = __builtin_amdgcn_mfma_f32_16x16x32_bf16(A1, Bl, acc[1], 0, 0, 0);
    acc[2] = __builtin_amdgcn_mfma_f32_16x16x32_bf16(A2, Bl, acc[2], 0, 0, 0);
    acc[3] = __builtin_amdgcn_mfma_f32_16x16x32_bf16(A3, Bl, acc[3], 0, 0, 0);
  }
  float* pc = part + (size_t)(kc * 32 + bh) * 64 * 64;
#pragma unroll
  for (int m = 0; m < 4; ++m){
    int row = m * 16 + lk * 4;
#pragma unroll
    for (int j = 0; j < 4; ++j)
      pc[(size_t)(row + j) * 64 + w * 16 + lr] = acc[m][j];
  }
}

// ---------- K8b: deterministic reduction of PV partials (R3-R18 validated) ----------
__global__ void pv_reduce(const float* __restrict__ part, float* __restrict__ ctx,
                          const int* __restrict__ qvlp, const int* __restrict__ kvlp){
  int bh = blockIdx.y, r = blockIdx.x;
  int u = compute_u(qvlp[0]);
  if (r >= u) return;
  int kvlv = kvlp[0]; if (kvlv > 2048) kvlv = 2048; if (kvlv < 0) kvlv = 0;
  int kcmax = (kvlv + 127) / 128;
  int d = threadIdx.x;   // 64
  float s = 0.f;
  for (int kc = 0; kc < kcmax; ++kc)
    s += part[(size_t)((kc * 32 + bh) * 64 + r) * 64 + d];
  ctx[(size_t)(bh * 64 + r) * 64 + d] = s;
}

// ---------- K9a: OH[bh][64][cols] = ctx(64x64) @ Wo_h^T slice (R18 validated) ----------
__global__ __launch_bounds__(256) void oh_mfma2(
    const float* __restrict__ ctx, const u16* __restrict__ WO1,
    const u16* __restrict__ WO2, float* __restrict__ OH,
    const int* __restrict__ qvlp)
{
  int cs = blockIdx.x;                  // 0..15
  int bh = blockIdx.y; int h = bh & 15;
  int t = threadIdx.x;
  int u = compute_u(qvlp[0]);
  __shared__ __align__(16) u16 CT[64 * 128];   // ctx split-bf16 [64 rows][hi|lo]
  for (int e = t; e < 4096; e += 256){
    int i = e >> 6, d = e & 63;
    float s = (i < u) ? ctx[(size_t)(bh * 64 + i) * 64 + d] : 0.f;
    u16 hi = f2bf(s);
    CT[i * 128 + d] = hi;
    CT[i * 128 + 64 + d] = f2bf(s - bf2f(hi));
  }
  __syncthreads();
  int wave = t >> 6, lane = t & 63;
  int lr = lane & 15, lk = lane >> 4;
  bf16x8 ah[4][2], al[4][2];
#pragma unroll
  for (int m = 0; m < 4; ++m){
    const u16* crow = &CT[(m * 16 + lr) * 128];
#pragma unroll
    for (int ks = 0; ks < 2; ++ks){
      ah[m][ks] = *reinterpret_cast<const bf16x8*>(&crow[ks * 32 + lk * 8]);
      al[m][ks] = *reinterpret_cast<const bf16x8*>(&crow[64 + ks * 32 + lk * 8]);
    }
  }
  int c = cs * 4 + wave;                // col-frag 0..63 (16 cols each)
  const u16* w1r = &WO1[(size_t)(c * 16 + lr) * 1024 + h * 64];
  const u16* w2r = &WO2[(size_t)(c * 16 + lr) * 1024 + h * 64];
  bf16x8 bh0 = *reinterpret_cast<const bf16x8*>(&w1r[lk * 8]);
  bf16x8 bh1 = *reinterpret_cast<const bf16x8*>(&w1r[32 + lk * 8]);
  bf16x8 bl0 = *reinterpret_cast<const bf16x8*>(&w2r[lk * 8]);
  bf16x8 bl1 = *reinterpret_cast<const bf16x8*>(&w2r[32 + lk * 8]);
  float* ohb = OH + (size_t)bh * 64 * 1024;
  f32x4 acc[4] = {};
#pragma unroll
  for (int m = 0; m < 4; ++m){
    acc[m] = __builtin_amdgcn_mfma_f32_16x16x32_bf16(ah[m][0], bh0, acc[m], 0, 0, 0);
    acc[m] = __builtin_amdgcn_mfma_f32_16x16x32_bf16(ah[m][1], bh1, acc[m], 0, 0, 0);
    acc[m] = __builtin_amdgcn_mfma_f32_16x16x32_bf16(ah[m][0], bl0, acc[m], 0, 0, 0);
    acc[m] = __builtin_amdgcn_mfma_f32_16x16x32_bf16(ah[m][1], bl1, acc[m], 0, 0, 0);
    acc[m] = __builtin_amdgcn_mfma_f32_16x16x32_bf16(al[m][0], bh0, acc[m], 0, 0, 0);
    acc[m] = __builtin_amdgcn_mfma_f32_16x16x32_bf16(al[m][1], bh1, acc[m], 0, 0, 0);
#pragma unroll
    for (int j = 0; j < 4; ++j)
      ohb[(size_t)(m * 16 + lk * 4 + j) * 1024 + c * 16 + lr] = acc[m][j];
  }
}

// ---------- K9b: out = bo + sum_{h in hmask} OH[bh][seli] (R18 validated) ----------
__global__ __launch_bounds__(256) void out_assemble(
    const float* __restrict__ OH, const float* __restrict__ bo,
    const unsigned int* __restrict__ hmask, const unsigned char* __restrict__ seli,
    float* __restrict__ out)
{
  int row = blockIdx.x;                 // b*2048 + l
  int b = row >> 11, l = row & 2047;
  int t = threadIdx.x;
  float acc[4];
#pragma unroll
  for (int r = 0; r < 4; ++r) acc[r] = bo[t + r * 256];
  unsigned int m = hmask[row];
  while (m){
    int h = __ffs(m) - 1; m &= (m - 1);
    int bh = b * 16 + h;
    int i = (int)seli[(size_t)bh * 2048 + l];
    const float* orow = OH + ((size_t)bh * 64 + i) * 1024;
#pragma unroll
    for (int r = 0; r < 4; ++r) acc[r] += orow[t + r * 256];
  }
  float* dst = out + (size_t)row * 1024;
#pragma unroll
  for (int r = 0; r < 4; ++r) dst[t + r * 256] = acc[r];
}

__global__ void fail_fill(float* o, int n){
  int i = blockIdx.x * 256 + threadIdx.x;
  if (i < n) o[i] = 12345.0f;
}

// ---------------------------------------------------------------------------
extern "C" void kernel_launch(void* const* d_in, const int* in_sizes, int n_in,
                              void* d_out, int out_size, void* d_ws, size_t ws_size,
                              hipStream_t stream)
{
  const float* query = (const float*)d_in[0];
  const float* key   = (const float*)d_in[1];
  const float* value = (const float*)d_in[2];
  const float* maskp = (const float*)d_in[3];
  const float* Wq = (const float*)d_in[4];
  const float* bq = (const float*)d_in[5];
  const float* Wk = (const float*)d_in[6];
  const float* bk = (const float*)d_in[7];
  const float* Wv = (const float*)d_in[8];
  const float* bv = (const float*)d_in[9];
  const float* Wo = (const float*)d_in[10];
  const float* bo = (const float*)d_in[11];
  const int* qvl = (const int*)d_in[12];
  const int* kvl = (const int*)d_in[13];
  float* out = (float*)d_out;

  char* ws = (char*)d_ws;
  size_t off = 0;
  auto alloc = [&](size_t bytes) -> void* {
    void* p = ws + off;
    off = (off + bytes + 255) & ~(size_t)255;
    return p;
  };
  u16* X1 = (u16*)alloc(3ull * 4194304 * 2);
  u16* X2 = (u16*)alloc(3ull * 4194304 * 2);
  u16* W1 = (u16*)alloc(3ull * 1048576 * 2);
  u16* W2 = (u16*)alloc(3ull * 1048576 * 2);
  u16* WO1 = (u16*)alloc(1048576ull * 2);
  u16* WO2 = (u16*)alloc(1048576ull * 2);
  float* PROJ = (float*)alloc(3ull * 4194304 * 4);
  float* QN   = (float*)alloc(2ull * 16 * 2048 * 4);
  int*   TOPK = (int*)alloc(2ull * 16 * 64 * 4);
  unsigned char* SELI = (unsigned char*)alloc(2ull * 16 * 2048);
  unsigned int* HMASK = (unsigned int*)alloc(2ull * 2048 * 4);
  u16*   SC   = (u16*)alloc(2048ull * 2048 * 2);
  u16*   QS   = (u16*)alloc(32ull * 64 * 128 * 2);
  float* CTX  = (float*)alloc(32ull * 64 * 64 * 4);
  float* OH   = (float*)alloc(32ull * 64 * 1024 * 4);

  // KS (split-bf16 K) aliases the PROJ z==1 slice (exactly 16.78 MB)
  u16* KS = (u16*)(PROJ + 1ull * 4194304);
  // VT (split-bf16 transposed V) aliases the PROJ z==2 slice (exactly 16.78 MB)
  u16* VT = (u16*)(PROJ + 2ull * 4194304);
  // PV partials alias X1 (24 MB, dead after gemm_proj): 16*32*64*64*4 = 8.4 MB
  float* PART = (float*)X1;

  if (ws_size < off){
    fail_fill<<<(out_size + 255) / 256, 256, 0, stream>>>(out, out_size);
    return;
  }

  expand_kernel<<<8192, 256, 0, stream>>>(query, key, value, Wq, Wk, Wv, Wo,
                                          X1, X2, W1, W2, WO1, WO2, HMASK);
  gemm_proj<<<dim3(8, 32, 3), 256, 0, stream>>>(X1, X2, W1, W2, bq, bk, bv, PROJ, QN);
  topk_kernel<<<32, 256, 0, stream>>>(QN, TOPK, SELI, HMASK, PROJ, QS, qvl);
  scores_mfma<<<dim3(16, 32), 256, 0, stream>>>(QS, KS, TOPK, maskp, SC, qvl, kvl);
  softmax_kernel<<<dim3(64, 32), 256, 0, stream>>>(SC, qvl, kvl);
  pv_mfma<<<dim3(16, 32), 256, 0, stream>>>(SC, VT, PART, kvl);
  pv_reduce<<<dim3(64, 32), 64, 0, stream>>>(PART, CTX, qvl, kvl);
  oh_mfma2<<<dim3(16, 32), 256, 0, stream>>>(CTX, WO1, WO2, OH, qvl);
  out_assemble<<<4096, 256, 0, stream>>>(OH, bo, HMASK, SELI, out);
}

// Round 20
// 210.806 us; speedup vs baseline: 1.5363x; 1.0014x over previous
//
#include <hip/hip_runtime.h>

typedef unsigned short u16;
typedef __bf16 bf16x8 __attribute__((ext_vector_type(8)));
typedef float f32x4 __attribute__((ext_vector_type(4)));

// ---------- numeric helpers (RNE f32<->bf16, matching XLA/ml_dtypes) ----------
__device__ __forceinline__ u16 f2bf(float f){
  unsigned int x = __float_as_uint(f);
  unsigned int r = (x + 0x7FFFu + ((x >> 16) & 1u)) >> 16;
  return (u16)r;
}
__device__ __forceinline__ float bf2f(u16 u){
  return __uint_as_float(((unsigned int)u) << 16);
}
__device__ __forceinline__ int compute_u(int qvlv){
  int mm = qvlv > 2 ? qvlv : 2;
  int u = (int)(5.0 * log((double)mm));   // FACTOR=5.0, python int() truncation
  if (u < 1) u = 1;
  if (u > 64) u = 64;
  return u;
}
__device__ __forceinline__ void gload_lds16(const void* g, void* l){
  __builtin_amdgcn_global_load_lds(
      (const __attribute__((address_space(1))) void*)g,
      (__attribute__((address_space(3))) void*)l, 16, 0, 0);
}

// ---------- K1: split f32 -> 2 bf16 levels (16B stores); X: q/k/v, W: Wq/Wk/Wv/Wo ----------
__global__ void expand_kernel(const float* __restrict__ xq, const float* __restrict__ xk,
                              const float* __restrict__ xv,
                              const float* __restrict__ wq, const float* __restrict__ wk,
                              const float* __restrict__ wv, const float* __restrict__ wo,
                              u16* __restrict__ X1, u16* __restrict__ X2,
                              u16* __restrict__ W1, u16* __restrict__ W2,
                              u16* __restrict__ WO1, u16* __restrict__ WO2,
                              unsigned int* __restrict__ hmask)
{
  int t = threadIdx.x;
  size_t g = (size_t)blockIdx.x * 256 + t;      // one group = 8 floats
  if (g < 4096) hmask[g] = 0;
  const float* src; u16 *d1, *d2;
  if (g < 1572864ull) {                 // X part: 3 * 4194304 / 8
    int p = (int)(g >> 19);
    size_t e = (g & 524287ull) * 8;
    src = (p == 0 ? xq : (p == 1 ? xk : xv)) + e;
    size_t o = (size_t)p * 4194304ull + e;
    d1 = X1 + o; d2 = X2 + o;
  } else {                              // W part: 4 * 1048576 / 8
    size_t wg = g - 1572864ull;
    int p = (int)(wg >> 17);
    size_t e = (wg & 131071ull) * 8;
    src = (p == 0 ? wq : (p == 1 ? wk : (p == 2 ? wv : wo))) + e;
    if (p < 3){
      size_t o = (size_t)p * 1048576ull + e;
      d1 = W1 + o; d2 = W2 + o;
    } else {
      d1 = WO1 + e; d2 = WO2 + e;
    }
  }
  float4 a = *reinterpret_cast<const float4*>(src);
  float4 b = *reinterpret_cast<const float4*>(src + 4);
  float xs[8] = {a.x, a.y, a.z, a.w, b.x, b.y, b.z, b.w};
  unsigned int hw[4], lw[4];
#pragma unroll
  for (int i = 0; i < 4; ++i){
    u16 h0 = f2bf(xs[2*i]);     u16 l0 = f2bf(xs[2*i]     - bf2f(h0));
    u16 h1 = f2bf(xs[2*i + 1]); u16 l1 = f2bf(xs[2*i + 1] - bf2f(h1));
    hw[i] = (unsigned int)h0 | ((unsigned int)h1 << 16);
    lw[i] = (unsigned int)l0 | ((unsigned int)l1 << 16);
  }
  *reinterpret_cast<uint4*>(d1) = make_uint4(hw[0], hw[1], hw[2], hw[3]);
  *reinterpret_cast<uint4*>(d2) = make_uint4(lw[0], lw[1], lw[2], lw[3]);
}

// ---------- K3: split-precision bf16 MFMA GEMM  C = X @ W^T + bias ----------
// R19-validated (FROZEN): BM=128 / 4 waves (2x2), dbuf 64KB, 2 blocks/CU.
// z=0: Q -> f32 PROJ + qn; z=1: K -> KS split-bf16; z=2: V -> VT split-bf16 T.
__global__ __launch_bounds__(256, 2) void gemm_proj(
    const u16* __restrict__ X1, const u16* __restrict__ X2,
    const u16* __restrict__ W1, const u16* __restrict__ W2,
    const float* __restrict__ bq, const float* __restrict__ bk, const float* __restrict__ bv,
    float* __restrict__ PROJ, float* __restrict__ qn)
{
  int z = blockIdx.z;
  // XCD-chunked bijective swizzle: 256 blocks/z, 8 XCDs, 32 per XCD
  int orig = blockIdx.x + blockIdx.y * 8;          // 0..255
  int wgid = (orig & 7) * 32 + (orig >> 3);
  int bx = wgid & 7, by = wgid >> 3;               // bx<8, by<32

  const u16* Xa0 = X1 + (size_t)z * 4194304;
  const u16* Xa1 = X2 + (size_t)z * 4194304;
  const u16* Wb0 = W1 + (size_t)z * 1048576;
  const u16* Wb1 = W2 + (size_t)z * 1048576;
  const float* bias = (z == 0) ? bq : (z == 1 ? bk : bv);
  float* C = PROJ + (size_t)z * 4194304;

  // set: A0[128x32]@0, A1@4096, B0[128x32]@8192, B1@12288 (16384 u16 = 32KB)
  __shared__ __align__(16) u16 T[2 * 16384];       // 64 KB
  u16* SET0 = T;
  u16* SET1 = T + 16384;

  int t = threadIdx.x;
  int wave = t >> 6, lane = t & 63;
  int wm = wave >> 1, wn = wave & 1;               // 2 x 2 wave grid
  int lr = lane & 15, lk = lane >> 4;
  int rowA = by * 128, rowB = bx * 128;
  f32x4 acc[4][4] = {};
  bf16x8 afA[4], afB[4], bgA[4], bgB[4];

#define STAGET(dstbase, G, R0)                                                \
  {                                                                           \
    _Pragma("unroll")                                                         \
    for (int i = 0; i < 2; ++i){                                              \
      int p = i * 256 + t;                                                    \
      int r = p >> 2;                                                         \
      int c = (p & 3) ^ ((r >> 1) & 3);                                       \
      gload_lds16(G + (size_t)(R0 + r) * 1024 + pk + c * 8,                   \
                  (dstbase) + p * 8);                                         \
    }                                                                         \
  }
#define STAGE_SET(S)                                                          \
  {                                                                           \
    STAGET((S), Xa0, rowA); STAGET((S) + 4096, Xa1, rowA);                    \
    STAGET((S) + 8192, Wb0, rowB); STAGET((S) + 12288, Wb1, rowB);            \
  }
#define LOADA(dst, tile)                                                      \
  {                                                                           \
    _Pragma("unroll")                                                         \
    for (int m = 0; m < 4; ++m){                                              \
      int r = wm * 64 + m * 16 + lr;                                          \
      dst[m] = *reinterpret_cast<const bf16x8*>(                              \
          &(tile)[r * 32 + ((lk ^ ((r >> 1) & 3)) << 3)]);                    \
    }                                                                         \
  }
#define LOADB(dst, tile)                                                      \
  {                                                                           \
    _Pragma("unroll")                                                         \
    for (int n = 0; n < 4; ++n){                                              \
      int r = wn * 64 + n * 16 + lr;                                          \
      dst[n] = *reinterpret_cast<const bf16x8*>(                              \
          &(tile)[r * 32 + ((lk ^ ((r >> 1) & 3)) << 3)]);                    \
    }                                                                         \
  }
#define GRPX(A_, B_)                                                          \
  {                                                                           \
    __builtin_amdgcn_s_setprio(1);                                            \
    _Pragma("unroll")                                                         \
    for (int m = 0; m < 4; ++m)                                               \
      _Pragma("unroll")                                                       \
      for (int n = 0; n < 4; ++n)                                             \
        acc[m][n] = __builtin_amdgcn_mfma_f32_16x16x32_bf16(A_[m], B_[n],     \
                                                            acc[m][n], 0,0,0);\
    __builtin_amdgcn_s_setprio(0);                                            \
  }

  {                                    // prologue: stage chunk 0
    int pk = 0;
    STAGE_SET(SET0);
  }
  __syncthreads();

  for (int kt = 0; kt < 32; ++kt){
    u16* CUR = (kt & 1) ? SET1 : SET0;
    u16* NXT = (kt & 1) ? SET0 : SET1;
    if (kt < 31){
      int pk = (kt + 1) * 32;
      STAGE_SET(NXT);                  // issue next-chunk loads (hidden under MFMA)
    }
    __builtin_amdgcn_sched_barrier(0); // keep stage-issue ahead of compute
    u16* A0t = CUR;         u16* A1t = CUR + 4096;
    u16* B0t = CUR + 8192;  u16* B1t = CUR + 12288;
    LOADA(afA, A0t); LOADB(bgA, B0t);
    LOADB(bgB, B1t); GRPX(afA, bgA);   // A0*B0
    LOADA(afB, A1t); GRPX(afA, bgB);   // A0*B1
                     GRPX(afB, bgA);   // A1*B0
    __syncthreads();                   // drains vmcnt: next chunk staged & visible
  }
#undef STAGET
#undef STAGE_SET
#undef LOADA
#undef LOADB
#undef GRPX

  if (z == 0){
    float sq[4][4] = {};                      // [m][j] partial row-norms
#pragma unroll
    for (int m = 0; m < 4; ++m){
      int row0 = by * 128 + wm * 64 + m * 16 + lk * 4;
#pragma unroll
      for (int n = 0; n < 4; ++n){
        int col = bx * 128 + wn * 64 + n * 16 + lr;
        float bb = bias[col];
#pragma unroll
        for (int j = 0; j < 4; ++j){
          float v = acc[m][n][j] + bb;
          C[(size_t)(row0 + j) * 1024 + col] = v;
          sq[m][j] += v * v;
        }
      }
    }
    int hh = bx * 2 + wn;                     // this (bx,wn) covers head hh fully
#pragma unroll
    for (int m = 0; m < 4; ++m){
#pragma unroll
      for (int j = 0; j < 4; ++j){
        float s = sq[m][j];
        s += __shfl_xor(s, 1);
        s += __shfl_xor(s, 2);
        s += __shfl_xor(s, 4);
        s += __shfl_xor(s, 8);
        if (lr == 0){
          int row = by * 128 + wm * 64 + m * 16 + lk * 4 + j;
          qn[(size_t)((row >> 11) * 16 + hh) * 2048 + (row & 2047)] = s;
        }
      }
    }
  } else if (z == 1){
    u16* KS = (u16*)C;   // [32][2048][128] u16 (hi|lo planes)
#pragma unroll
    for (int m = 0; m < 4; ++m){
      int r0 = by * 128 + wm * 64 + m * 16 + lk * 4;
      int b = r0 >> 11, kb = r0 & 2047;
#pragma unroll
      for (int n = 0; n < 4; ++n){
        int c = bx * 128 + wn * 64 + n * 16 + lr;
        float bb = bias[c];
        int h = c >> 6, d = c & 63;
#pragma unroll
        for (int j = 0; j < 4; ++j){
          float v = acc[m][n][j] + bb;
          u16 hi = f2bf(v);
          u16 lo = f2bf(v - bf2f(hi));
          size_t base = ((size_t)(b * 16 + h) * 2048 + (size_t)(kb + j)) * 128;
          KS[base + d] = hi;
          KS[base + 64 + d] = lo;
        }
      }
    }
  } else {
    u16* VT = (u16*)C;   // [32][128][2048] u16
#pragma unroll
    for (int m = 0; m < 4; ++m){
      int r0 = by * 128 + wm * 64 + m * 16 + lk * 4;
      int b = r0 >> 11, kb = r0 & 2047;
#pragma unroll
      for (int n = 0; n < 4; ++n){
        int c = bx * 128 + wn * 64 + n * 16 + lr;
        float bb = bias[c];
        int h = c >> 6, d = c & 63;
        u16 hi[4], lo[4];
#pragma unroll
        for (int j = 0; j < 4; ++j){
          float v = acc[m][n][j] + bb;
          hi[j] = f2bf(v);
          lo[j] = f2bf(v - bf2f(hi[j]));
        }
        size_t base = ((size_t)(b * 16 + h) * 128) * 2048 + (size_t)kb;
        *reinterpret_cast<ushort4*>(&VT[base + (size_t)d * 2048]) =
            make_ushort4(hi[0], hi[1], hi[2], hi[3]);
        *reinterpret_cast<ushort4*>(&VT[base + (size_t)(64 + d) * 2048]) =
            make_ushort4(lo[0], lo[1], lo[2], lo[3]);
      }
    }
  }
}

// ---------- K5: top-u per (b,h): 1-wave barrier-free selection + QS gather ----------
__global__ __launch_bounds__(256) void topk_kernel(
    const float* __restrict__ qn, int* __restrict__ topk,
    unsigned char* __restrict__ seli, unsigned int* __restrict__ hmask,
    const float* __restrict__ PROJ, u16* __restrict__ QS,
    const int* __restrict__ qvlp){
  int bh = blockIdx.x; int b = bh >> 4, h = bh & 15;
  int u = compute_u(qvlp[0]);
  int t = threadIdx.x;
  __shared__ int sidx_l[64];
  if (t < 64){                              // wave 0 only: selection
    int lane = t;
    float v[32];
#pragma unroll
    for (int j = 0; j < 32; ++j) v[j] = qn[(size_t)bh * 2048 + j * 64 + lane];
    for (int it = 0; it < u; ++it){
      float bv = v[0]; int bi = lane;
#pragma unroll
      for (int j = 1; j < 32; ++j){
        if (v[j] > bv){ bv = v[j]; bi = j * 64 + lane; }   // strict >: lowest j
      }
#pragma unroll
      for (int off = 1; off < 64; off <<= 1){
        float ov = __shfl_xor(bv, off);
        int   oi = __shfl_xor(bi, off);
        if (ov > bv || (ov == bv && oi < bi)){ bv = ov; bi = oi; }
      }
      if (lane == 0){
        topk[bh * 64 + it] = bi;
        seli[(size_t)bh * 2048 + bi] = (unsigned char)it;
        atomicOr(&hmask[b * 2048 + bi], 1u << h);
        sidx_l[it] = bi;
      }
#pragma unroll
      for (int j = 0; j < 32; ++j)          // static-index suppression
        if (j * 64 + lane == bi) v[j] = -3.4e38f;
    }
  }
  __syncthreads();
  for (int e = t; e < 64 * 64; e += 256){   // gather phase: all 256 threads
    int i = e >> 6, d = e & 63;
    float v = 0.f;
    if (i < u) v = PROJ[(size_t)(b * 2048 + sidx_l[i]) * 1024 + h * 64 + d];
    u16 hi = f2bf(v);
    u16 lo = f2bf(v - bf2f(hi));
    QS[(size_t)bh * 8192 + i * 128 + d] = hi;
    QS[(size_t)bh * 8192 + i * 128 + 64 + d] = lo;
  }
}

// ---------- K6b: scores via MFMA: S = Q_sel @ K^T, bf16 round + bf16 mask add ----------
__global__ __launch_bounds__(256) void scores_mfma(
    const u16* __restrict__ QS, const u16* __restrict__ KS,
    const int* __restrict__ topk, const float* __restrict__ maskp,
    u16* __restrict__ sc, const int* __restrict__ qvlp, const int* __restrict__ kvlp)
{
  int bh = blockIdx.y;
  int kvlv = kvlp[0]; if (kvlv > 2048) kvlv = 2048; if (kvlv < 0) kvlv = 0;
  int u = compute_u(qvlp[0]);
  int k0 = blockIdx.x * 128;
  if (k0 >= kvlv) return;
  int t = threadIdx.x, wave = t >> 6, lane = t & 63;
  int lr = lane & 15, lk = lane >> 4;
  __shared__ int idx_l[64];
  if (t < 64) idx_l[t] = (t < u) ? topk[bh * 64 + t] : 0;
  __syncthreads();
  const u16* Qb = QS + (size_t)bh * 8192;
  const u16* Kb = KS + (size_t)bh * 2048 * 128;
  bf16x8 ah[2], al[2];
#pragma unroll
  for (int ks = 0; ks < 2; ++ks){
    const u16* qrow = &Qb[(wave * 16 + lr) * 128];
    ah[ks] = *reinterpret_cast<const bf16x8*>(&qrow[ks * 32 + lk * 8]);
    al[ks] = *reinterpret_cast<const bf16x8*>(&qrow[64 + ks * 32 + lk * 8]);
  }
  f32x4 acc[8] = {};
#pragma unroll
  for (int n = 0; n < 8; ++n){
    const u16* krow = &Kb[(size_t)(k0 + n * 16 + lr) * 128];
    bf16x8 bh0 = *reinterpret_cast<const bf16x8*>(&krow[lk * 8]);
    bf16x8 bh1 = *reinterpret_cast<const bf16x8*>(&krow[32 + lk * 8]);
    bf16x8 bl0 = *reinterpret_cast<const bf16x8*>(&krow[64 + lk * 8]);
    bf16x8 bl1 = *reinterpret_cast<const bf16x8*>(&krow[96 + lk * 8]);
    acc[n] = __builtin_amdgcn_mfma_f32_16x16x32_bf16(ah[0], bh0, acc[n], 0, 0, 0);
    acc[n] = __builtin_amdgcn_mfma_f32_16x16x32_bf16(ah[0], bl0, acc[n], 0, 0, 0);
    acc[n] = __builtin_amdgcn_mfma_f32_16x16x32_bf16(al[0], bh0, acc[n], 0, 0, 0);
    acc[n] = __builtin_amdgcn_mfma_f32_16x16x32_bf16(al[0], bl0, acc[n], 0, 0, 0);
    acc[n] = __builtin_amdgcn_mfma_f32_16x16x32_bf16(ah[1], bh1, acc[n], 0, 0, 0);
    acc[n] = __builtin_amdgcn_mfma_f32_16x16x32_bf16(ah[1], bl1, acc[n], 0, 0, 0);
    acc[n] = __builtin_amdgcn_mfma_f32_16x16x32_bf16(al[1], bh1, acc[n], 0, 0, 0);
    acc[n] = __builtin_amdgcn_mfma_f32_16x16x32_bf16(al[1], bl1, acc[n], 0, 0, 0);
  }
#pragma unroll
  for (int n = 0; n < 8; ++n){
    int k = k0 + n * 16 + lr;
    if (k >= kvlv) continue;
#pragma unroll
    for (int j = 0; j < 4; ++j){
      int i = wave * 16 + lk * 4 + j;
      if (i >= u) continue;
      float s = acc[n][j] * 0.125f;               // / sqrt(64)
      u16 xb = f2bf(s);                           // scores.astype(bf16)
      u16 mb = f2bf(maskp[(size_t)idx_l[i] * 2048 + k]);  // attn_mask.astype(bf16)
      u16 xm = f2bf(bf2f(xb) + bf2f(mb));         // bf16 add
      sc[(size_t)(bh * 64 + i) * 2048 + k] = xm;
    }
  }
}

// ---------- K7: exact bf16 softmax emulation; vectorized 16B row I/O ----------
__global__ __launch_bounds__(256) void softmax_kernel(
    u16* __restrict__ sc, const int* __restrict__ qvlp, const int* __restrict__ kvlp){
  int bh = blockIdx.y, i = blockIdx.x;
  int u = compute_u(qvlp[0]);
  if (i >= u) return;
  int kvlv = kvlp[0]; if (kvlv > 2048) kvlv = 2048; if (kvlv < 0) kvlv = 0;
  u16* row = sc + (size_t)(bh * 64 + i) * 2048;
  int t = threadIdx.x;
  ushort4 va = *reinterpret_cast<const ushort4*>(&row[t * 8]);
  ushort4 vb = *reinterpret_cast<const ushort4*>(&row[t * 8 + 4]);
  u16 xs[8] = {va.x, va.y, va.z, va.w, vb.x, vb.y, vb.z, vb.w};
  float x[8];
  float lm = -3.4e38f;
#pragma unroll
  for (int j = 0; j < 8; ++j){
    int k = t * 8 + j;
    x[j] = (k < kvlv) ? bf2f(xs[j]) : -3.4e38f;
    lm = fmaxf(lm, x[j]);
  }
  __shared__ float red[256];
  red[t] = lm; __syncthreads();
  for (int s = 128; s > 0; s >>= 1){ if (t < s) red[t] = fmaxf(red[t], red[t+s]); __syncthreads(); }
  float m = red[0];
  __syncthreads();
  float e[8]; float ls = 0.f;
#pragma unroll
  for (int j = 0; j < 8; ++j){
    int k = t * 8 + j;
    if (k < kvlv){
      u16 ub = f2bf(x[j] - m);            // bf16 subtract
      u16 eb = f2bf(expf(bf2f(ub)));      // bf16 exp
      e[j] = bf2f(eb);
      ls += e[j];
    } else e[j] = 0.f;
  }
  red[t] = ls; __syncthreads();
  for (int s = 128; s > 0; s >>= 1){ if (t < s) red[t] += red[t+s]; __syncthreads(); }
  float S = red[0];                       // f32 accumulation (jnp.sum upcast)
  float Sb = bf2f(f2bf(S));               // downcast back to bf16
  u16 os[8];
#pragma unroll
  for (int j = 0; j < 8; ++j){
    int k = t * 8 + j;
    os[j] = (k < kvlv) ? f2bf(e[j] / Sb) : (u16)0;   // bf16 divide
  }
  *reinterpret_cast<ushort4*>(&row[t * 8])     = make_ushort4(os[0], os[1], os[2], os[3]);
  *reinterpret_cast<ushort4*>(&row[t * 8 + 4]) = make_ushort4(os[4], os[5], os[6], os[7]);
}

// ---------- K8a: PV via MFMA, no LDS. part[kc][bh][64 rows][64 d] ----------
__global__ void pv_mfma(const u16* __restrict__ probs, const u16* __restrict__ VT,
                        float* __restrict__ part, const int* __restrict__ kvlp)
{
  int bh = blockIdx.y; int b = bh >> 4, h = bh & 15;
  int kvlv = kvlp[0]; if (kvlv > 2048) kvlv = 2048; if (kvlv < 0) kvlv = 0;
  int kc = blockIdx.x;
  int k0 = kc * 128;
  if (k0 >= kvlv) return;
  int t = threadIdx.x, w = t >> 6, lane = t & 63;
  int lr = lane & 15, lk = lane >> 4;
  const u16* Pb = probs + (size_t)bh * 64 * 2048;
  const u16* Vb = VT + (size_t)(b * 16 + h) * 128 * 2048;
  f32x4 acc[4] = {};
#pragma unroll
  for (int ks = 0; ks < 4; ++ks){
    int kk = k0 + ks * 32 + lk * 8;
    bf16x8 A0 = *reinterpret_cast<const bf16x8*>(Pb + (size_t)(lr     ) * 2048 + kk);
    bf16x8 A1 = *reinterpret_cast<const bf16x8*>(Pb + (size_t)(lr + 16) * 2048 + kk);
    bf16x8 A2 = *reinterpret_cast<const bf16x8*>(Pb + (size_t)(lr + 32) * 2048 + kk);
    bf16x8 A3 = *reinterpret_cast<const bf16x8*>(Pb + (size_t)(lr + 48) * 2048 + kk);
    bf16x8 Bh = *reinterpret_cast<const bf16x8*>(Vb + (size_t)(w * 16 + lr     ) * 2048 + kk);
    bf16x8 Bl = *reinterpret_cast<const bf16x8*>(Vb + (size_t)(w * 16 + lr + 64) * 2048 + kk);
    acc[0] = __builtin_amdgcn_mfma_f32_16x16x32_bf16(A0, Bh, acc[0], 0, 0, 0);
    acc[1] = __builtin_amdgcn_mfma_f32_16x16x32_bf16(A1, Bh, acc[1], 0, 0, 0);
    acc[2] = __builtin_amdgcn_mfma_f32_16x16x32_bf16(A2, Bh, acc[2], 0, 0, 0);
    acc[3] = __builtin_amdgcn_mfma_f32_16x16x32_bf16(A3, Bh, acc[3], 0, 0, 0);
    acc[0] = __builtin_amdgcn_mfma_f32_16x16x32_bf16(A0, Bl, acc[0], 0, 0, 0);
    acc[1] = __builtin_amdgcn_mfma_f32_16x16x32_bf16(A1, Bl, acc[1], 0, 0, 0);
    acc[2] = __builtin_amdgcn_mfma_f32_16x16x32_bf16(A2, Bl, acc[2], 0, 0, 0);
    acc[3] = __builtin_amdgcn_mfma_f32_16x16x32_bf16(A3, Bl, acc[3], 0, 0, 0);
  }
  float* pc = part + (size_t)(kc * 32 + bh) * 64 * 64;
#pragma unroll
  for (int m = 0; m < 4; ++m){
    int row = m * 16 + lk * 4;
#pragma unroll
    for (int j = 0; j < 4; ++j)
      pc[(size_t)(row + j) * 64 + w * 16 + lr] = acc[m][j];
  }
}

// ---------- K8b: PV-partials reduction; 256-thr blocks, 4 rows each ----------
__global__ __launch_bounds__(256) void pv_reduce(
    const float* __restrict__ part, float* __restrict__ ctx,
    const int* __restrict__ qvlp, const int* __restrict__ kvlp){
  int bh = blockIdx.y, rg = blockIdx.x;       // rg < 16
  int t = threadIdx.x;
  int rr = t >> 6, d = t & 63;
  int r = rg * 4 + rr;
  int u = compute_u(qvlp[0]);
  if (r >= u) return;
  int kvlv = kvlp[0]; if (kvlv > 2048) kvlv = 2048; if (kvlv < 0) kvlv = 0;
  int kcmax = (kvlv + 127) / 128;
  float s = 0.f;
  for (int kc = 0; kc < kcmax; ++kc)
    s += part[(size_t)((kc * 32 + bh) * 64 + r) * 64 + d];
  ctx[(size_t)(bh * 64 + r) * 64 + d] = s;
}

// ---------- K9a: OH[bh][64][cols] = ctx(64x64) @ Wo_h^T slice (R18 validated) ----------
__global__ __launch_bounds__(256) void oh_mfma2(
    const float* __restrict__ ctx, const u16* __restrict__ WO1,
    const u16* __restrict__ WO2, float* __restrict__ OH,
    const int* __restrict__ qvlp)
{
  int cs = blockIdx.x;                  // 0..15
  int bh = blockIdx.y; int h = bh & 15;
  int t = threadIdx.x;
  int u = compute_u(qvlp[0]);
  __shared__ __align__(16) u16 CT[64 * 128];   // ctx split-bf16 [64 rows][hi|lo]
  for (int e = t; e < 4096; e += 256){
    int i = e >> 6, d = e & 63;
    float s = (i < u) ? ctx[(size_t)(bh * 64 + i) * 64 + d] : 0.f;
    u16 hi = f2bf(s);
    CT[i * 128 + d] = hi;
    CT[i * 128 + 64 + d] = f2bf(s - bf2f(hi));
  }
  __syncthreads();
  int wave = t >> 6, lane = t & 63;
  int lr = lane & 15, lk = lane >> 4;
  bf16x8 ah[4][2], al[4][2];
#pragma unroll
  for (int m = 0; m < 4; ++m){
    const u16* crow = &CT[(m * 16 + lr) * 128];
#pragma unroll
    for (int ks = 0; ks < 2; ++ks){
      ah[m][ks] = *reinterpret_cast<const bf16x8*>(&crow[ks * 32 + lk * 8]);
      al[m][ks] = *reinterpret_cast<const bf16x8*>(&crow[64 + ks * 32 + lk * 8]);
    }
  }
  int c = cs * 4 + wave;                // col-frag 0..63 (16 cols each)
  const u16* w1r = &WO1[(size_t)(c * 16 + lr) * 1024 + h * 64];
  const u16* w2r = &WO2[(size_t)(c * 16 + lr) * 1024 + h * 64];
  bf16x8 bh0 = *reinterpret_cast<const bf16x8*>(&w1r[lk * 8]);
  bf16x8 bh1 = *reinterpret_cast<const bf16x8*>(&w1r[32 + lk * 8]);
  bf16x8 bl0 = *reinterpret_cast<const bf16x8*>(&w2r[lk * 8]);
  bf16x8 bl1 = *reinterpret_cast<const bf16x8*>(&w2r[32 + lk * 8]);
  float* ohb = OH + (size_t)bh * 64 * 1024;
  f32x4 acc[4] = {};
#pragma unroll
  for (int m = 0; m < 4; ++m){
    acc[m] = __builtin_amdgcn_mfma_f32_16x16x32_bf16(ah[m][0], bh0, acc[m], 0, 0, 0);
    acc[m] = __builtin_amdgcn_mfma_f32_16x16x32_bf16(ah[m][1], bh1, acc[m], 0, 0, 0);
    acc[m] = __builtin_amdgcn_mfma_f32_16x16x32_bf16(ah[m][0], bl0, acc[m], 0, 0, 0);
    acc[m] = __builtin_amdgcn_mfma_f32_16x16x32_bf16(ah[m][1], bl1, acc[m], 0, 0, 0);
    acc[m] = __builtin_amdgcn_mfma_f32_16x16x32_bf16(al[m][0], bh0, acc[m], 0, 0, 0);
    acc[m] = __builtin_amdgcn_mfma_f32_16x16x32_bf16(al[m][1], bh1, acc[m], 0, 0, 0);
#pragma unroll
    for (int j = 0; j < 4; ++j)
      ohb[(size_t)(m * 16 + lk * 4 + j) * 1024 + c * 16 + lr] = acc[m][j];
  }
}

// ---------- K9b: out = bo + sum_{h in hmask} OH[bh][seli] (R18 validated) ----------
__global__ __launch_bounds__(256) void out_assemble(
    const float* __restrict__ OH, const float* __restrict__ bo,
    const unsigned int* __restrict__ hmask, const unsigned char* __restrict__ seli,
    float* __restrict__ out)
{
  int row = blockIdx.x;                 // b*2048 + l
  int b = row >> 11, l = row & 2047;
  int t = threadIdx.x;
  float acc[4];
#pragma unroll
  for (int r = 0; r < 4; ++r) acc[r] = bo[t + r * 256];
  unsigned int m = hmask[row];
  while (m){
    int h = __ffs(m) - 1; m &= (m - 1);
    int bh = b * 16 + h;
    int i = (int)seli[(size_t)bh * 2048 + l];
    const float* orow = OH + ((size_t)bh * 64 + i) * 1024;
#pragma unroll
    for (int r = 0; r < 4; ++r) acc[r] += orow[t + r * 256];
  }
  float* dst = out + (size_t)row * 1024;
#pragma unroll
  for (int r = 0; r < 4; ++r) dst[t + r * 256] = acc[r];
}

__global__ void fail_fill(float* o, int n){
  int i = blockIdx.x * 256 + threadIdx.x;
  if (i < n) o[i] = 12345.0f;
}

// ---------------------------------------------------------------------------
extern "C" void kernel_launch(void* const* d_in, const int* in_sizes, int n_in,
                              void* d_out, int out_size, void* d_ws, size_t ws_size,
                              hipStream_t stream)
{
  const float* query = (const float*)d_in[0];
  const float* key   = (const float*)d_in[1];
  const float* value = (const float*)d_in[2];
  const float* maskp = (const float*)d_in[3];
  const float* Wq = (const float*)d_in[4];
  const float* bq = (const float*)d_in[5];
  const float* Wk = (const float*)d_in[6];
  const float* bk = (const float*)d_in[7];
  const float* Wv = (const float*)d_in[8];
  const float* bv = (const float*)d_in[9];
  const float* Wo = (const float*)d_in[10];
  const float* bo = (const float*)d_in[11];
  const int* qvl = (const int*)d_in[12];
  const int* kvl = (const int*)d_in[13];
  float* out = (float*)d_out;

  char* ws = (char*)d_ws;
  size_t off = 0;
  auto alloc = [&](size_t bytes) -> void* {
    void* p = ws + off;
    off = (off + bytes + 255) & ~(size_t)255;
    return p;
  };
  u16* X1 = (u16*)alloc(3ull * 4194304 * 2);
  u16* X2 = (u16*)alloc(3ull * 4194304 * 2);
  u16* W1 = (u16*)alloc(3ull * 1048576 * 2);
  u16* W2 = (u16*)alloc(3ull * 1048576 * 2);
  u16* WO1 = (u16*)alloc(1048576ull * 2);
  u16* WO2 = (u16*)alloc(1048576ull * 2);
  float* PROJ = (float*)alloc(3ull * 4194304 * 4);
  float* QN   = (float*)alloc(2ull * 16 * 2048 * 4);
  int*   TOPK = (int*)alloc(2ull * 16 * 64 * 4);
  unsigned char* SELI = (unsigned char*)alloc(2ull * 16 * 2048);
  unsigned int* HMASK = (unsigned int*)alloc(2ull * 2048 * 4);
  u16*   SC   = (u16*)alloc(2048ull * 2048 * 2);
  u16*   QS   = (u16*)alloc(32ull * 64 * 128 * 2);
  float* CTX  = (float*)alloc(32ull * 64 * 64 * 4);
  float* OH   = (float*)alloc(32ull * 64 * 1024 * 4);

  // KS (split-bf16 K) aliases the PROJ z==1 slice (exactly 16.78 MB)
  u16* KS = (u16*)(PROJ + 1ull * 4194304);
  // VT (split-bf16 transposed V) aliases the PROJ z==2 slice (exactly 16.78 MB)
  u16* VT = (u16*)(PROJ + 2ull * 4194304);
  // PV partials alias X1 (24 MB, dead after gemm_proj): 16*32*64*64*4 = 8.4 MB
  float* PART = (float*)X1;

  if (ws_size < off){
    fail_fill<<<(out_size + 255) / 256, 256, 0, stream>>>(out, out_size);
    return;
  }

  expand_kernel<<<8192, 256, 0, stream>>>(query, key, value, Wq, Wk, Wv, Wo,
                                          X1, X2, W1, W2, WO1, WO2, HMASK);
  gemm_proj<<<dim3(8, 32, 3), 256, 0, stream>>>(X1, X2, W1, W2, bq, bk, bv, PROJ, QN);
  topk_kernel<<<32, 256, 0, stream>>>(QN, TOPK, SELI, HMASK, PROJ, QS, qvl);
  scores_mfma<<<dim3(16, 32), 256, 0, stream>>>(QS, KS, TOPK, maskp, SC, qvl, kvl);
  softmax_kernel<<<dim3(64, 32), 256, 0, stream>>>(SC, qvl, kvl);
  pv_mfma<<<dim3(16, 32), 256, 0, stream>>>(SC, VT, PART, kvl);
  pv_reduce<<<dim3(16, 32), 256, 0, stream>>>(PART, CTX, qvl, kvl);
  oh_mfma2<<<dim3(16, 32), 256, 0, stream>>>(CTX, WO1, WO2, OH, qvl);
  out_assemble<<<4096, 256, 0, stream>>>(OH, bo, HMASK, SELI, out);
}